// Round 15
// baseline (4273.966 us; speedup 1.0000x reference)
//
#include <hip/hip_runtime.h>
#include <cstdint>
#include <cstddef>

typedef unsigned short u16;
typedef unsigned int   u32;
typedef __bf16 bf16_t;
typedef bf16_t bf16x8 __attribute__((ext_vector_type(8)));
typedef float  f32x4  __attribute__((ext_vector_type(4)));
typedef u16    u16x4  __attribute__((ext_vector_type(4)));

// ---- problem constants ----
// H=3072 NH=24 HD=128 MLP_D=12288 IMG=1536 REF=512 TXT=256
// LQ = 1792, L2 = 2304, N1 = 21504, K2 = 15360

__device__ __forceinline__ float b2f(u16 b){ u32 u=((u32)b)<<16; float f; __builtin_memcpy(&f,&u,4); return f; }
__device__ __forceinline__ u16 f2b(float f){ u32 u; __builtin_memcpy(&u,&f,4); u = u + 0x7fffu + ((u>>16)&1u); return (u16)(u>>16); }
// gelu(x) = x * sigmoid(1.5957691*(x+0.044715x^3))
__device__ __forceinline__ float gelu_f(float x){
  const float u2 = 1.5957691216057308f*(x + 0.044715f*x*x*x);
  return x/(1.f + __expf(-u2));
}

__device__ __forceinline__ void gload_lds16(const void* g, void* l){
  __builtin_amdgcn_global_load_lds((const __attribute__((address_space(1))) void*)g,
                                   (__attribute__((address_space(3))) void*)l, 16, 0, 0);
}

template<int NW, bool MX>
__device__ __forceinline__ float bred(float v, float* red){
  #pragma unroll
  for (int o=32;o;o>>=1){ float u=__shfl_down(v,o,64); v = MX? fmaxf(v,u) : v+u; }
  const int t = threadIdx.x;
  if ((t&63)==0) red[t>>6]=v;
  __syncthreads();
  float r = red[0];
  #pragma unroll
  for (int i=1;i<NW;i++) r = MX? fmaxf(r,red[i]) : r+red[i];
  __syncthreads();
  return r;
}

// ---------------- mod GEMV ----------------
__global__ void modv_part(const float* __restrict__ vec, const float* __restrict__ W,
                          float* __restrict__ part){
  __shared__ float s[128];
  const int t = threadIdx.x;
  const int j = blockIdx.x*256 + t;
  const int i0 = blockIdx.y*128;
  if (t < 128){ float v = vec[i0+t]; s[t] = v/(1.f+__expf(-v)); }
  __syncthreads();
  float acc = 0.f;
  #pragma unroll 8
  for (int i=0;i<128;i++) acc += s[i]*W[(size_t)(i0+i)*9216 + j];
  part[(size_t)blockIdx.y*9216 + j] = acc;
}
__global__ void modv_reduce(const float* __restrict__ part, const float* __restrict__ mb,
                            float* __restrict__ modp){
  const int j = blockIdx.x*256 + threadIdx.x;
  float a = mb[j];
  #pragma unroll
  for (int c=0;c<24;c++) a += part[(size_t)c*9216 + j];
  modp[j] = a;
}

// ---------------- fp32 (K x N) -> bf16 transposed (N x K), 64x64 tile ----------------
__global__ __launch_bounds__(256)
void convT(const float* __restrict__ W, u16* __restrict__ Wt, int Kd, int Nd){
  __shared__ float Ls[64][65];
  const int t = threadIdx.x;
  const int n0 = blockIdx.x*64, k0 = blockIdx.y*64;
  const int tr = t>>4;        // 0..15
  const int tc = (t&15)*4;    // 0,4,...,60
  #pragma unroll
  for (int p=0;p<4;p++){
    const int kk = tr + p*16;
    const float4 v = *(const float4*)(W + (size_t)(k0+kk)*Nd + n0 + tc);
    Ls[kk][tc+0]=v.x; Ls[kk][tc+1]=v.y; Ls[kk][tc+2]=v.z; Ls[kk][tc+3]=v.w;
  }
  __syncthreads();
  #pragma unroll
  for (int p=0;p<4;p++){
    const int nn = tr + p*16;
    u16x4 o;
    o.x = f2b(Ls[tc+0][nn]); o.y = f2b(Ls[tc+1][nn]);
    o.z = f2b(Ls[tc+2][nn]); o.w = f2b(Ls[tc+3][nn]);
    *(u16x4*)(Wt + (size_t)(n0+nn)*Kd + k0 + tc) = o;
  }
}

__global__ void convertF2B(const float* __restrict__ src, u16* __restrict__ dst){
  const size_t i = ((size_t)blockIdx.x*256 + threadIdx.x)*4;
  const float4 v = *(const float4*)(src+i);
  u16x4 o; o.x=f2b(v.x); o.y=f2b(v.y); o.z=f2b(v.z); o.w=f2b(v.w);
  *(u16x4*)(dst+i) = o;
}

// ---------------- LN(x)*(1+scale)+shift -> xc (bf16) ----------------
__global__ void ln_modulate(const float* __restrict__ x, const float* __restrict__ modp,
                            u16* __restrict__ xc){
  __shared__ float red[4];
  const int row = blockIdx.x, t = threadIdx.x;
  const float* xr = x + (size_t)row*3072;
  float4 v[3]; float s=0.f, ss=0.f;
  #pragma unroll
  for (int k=0;k<3;k++){
    v[k] = *(const float4*)(xr + t*4 + k*1024);
    s  += v[k].x+v[k].y+v[k].z+v[k].w;
    ss += v[k].x*v[k].x+v[k].y*v[k].y+v[k].z*v[k].z+v[k].w*v[k].w;
  }
  s  = bred<4,false>(s, red);
  ss = bred<4,false>(ss, red);
  const float mean = s*(1.f/3072.f);
  const float inv = rsqrtf(ss*(1.f/3072.f)-mean*mean + 1e-6f);
  const int orow = row<1536 ? row : row+512;
  u16* o = xc + (size_t)orow*3072;
  const float* shiftp = modp; const float* scalep = modp+3072;
  #pragma unroll
  for (int k=0;k<3;k++){
    const int j = t*4 + k*1024;
    const float4 sc = *(const float4*)(scalep+j);
    const float4 sh = *(const float4*)(shiftp+j);
    u16x4 ov;
    ov.x = f2b((v[k].x-mean)*inv*(1.f+sc.x)+sh.x);
    ov.y = f2b((v[k].y-mean)*inv*(1.f+sc.y)+sh.y);
    ov.z = f2b((v[k].z-mean)*inv*(1.f+sc.z)+sh.z);
    ov.w = f2b((v[k].w-mean)*inv*(1.f+sc.w)+sh.w);
    *(u16x4*)(o+j) = ov;
  }
}

// ---------------- LN(r)*g+b -> xc rows [1536,2048) ----------------
__global__ void ln_ref(const float* __restrict__ rt, const float* __restrict__ g,
                       const float* __restrict__ b, u16* __restrict__ xc){
  __shared__ float red[4];
  const int row = blockIdx.x, t = threadIdx.x;
  const float* xr = rt + (size_t)row*3072;
  float4 v[3]; float s=0.f, ss=0.f;
  #pragma unroll
  for (int k=0;k<3;k++){
    v[k] = *(const float4*)(xr + t*4 + k*1024);
    s  += v[k].x+v[k].y+v[k].z+v[k].w;
    ss += v[k].x*v[k].x+v[k].y*v[k].y+v[k].z*v[k].z+v[k].w*v[k].w;
  }
  s  = bred<4,false>(s, red);
  ss = bred<4,false>(ss, red);
  const float mean = s*(1.f/3072.f);
  const float inv = rsqrtf(ss*(1.f/3072.f)-mean*mean + 1e-6f);
  u16* o = xc + (size_t)(1536+row)*3072;
  #pragma unroll
  for (int k=0;k<3;k++){
    const int j = t*4 + k*1024;
    const float4 gv = *(const float4*)(g+j);
    const float4 bv = *(const float4*)(b+j);
    u16x4 ov;
    ov.x = f2b((v[k].x-mean)*inv*gv.x+bv.x);
    ov.y = f2b((v[k].y-mean)*inv*gv.y+bv.y);
    ov.z = f2b((v[k].z-mean)*inv*gv.z+bv.z);
    ov.w = f2b((v[k].w-mean)*inv*gv.w+bv.w);
    *(u16x4*)(o+j) = ov;
  }
}

// ---------------- RMS-norm + RoPE on q,k from h ----------------
__global__ void qk_prep(const u16* __restrict__ h, const float* __restrict__ qg,
                        const float* __restrict__ kg, const float* __restrict__ cosb,
                        const float* __restrict__ sinb, u16* __restrict__ Q,
                        u16* __restrict__ Kb){
  __shared__ float red[4];
  const int row = blockIdx.x, hd = blockIdx.y, d = threadIdx.x; // 128 threads
  const u16* hr = h + (size_t)row*21504;
  const float kv = b2f(hr[3072 + hd*128 + d]);
  const bool doq = (row < 1536) || (row >= 2048);
  const float qv = doq ? b2f(hr[hd*128 + d]) : 0.f;
  float a = kv*kv, b = qv*qv;
  #pragma unroll
  for (int o=32;o;o>>=1){ a += __shfl_down(a,o,64); b += __shfl_down(b,o,64); }
  if ((d&63)==0){ red[(d>>6)*2] = a; red[(d>>6)*2+1] = b; }
  __syncthreads();
  const float kinv = rsqrtf((red[0]+red[2])*(1.f/128.f) + 1e-6f);
  const float qinv = rsqrtf((red[1]+red[3])*(1.f/128.f) + 1e-6f);
  float kn = kv*kinv*kg[d];
  float qn = qv*qinv*qg[d];
  if (row < 1536){
    const float c  = cosb[row*128 + d];
    const float sn = sinb[row*128 + d];
    const float ko = b2f(hr[3072 + hd*128 + (d^1)])*kinv*kg[d^1];
    const float qo = b2f(hr[hd*128 + (d^1)])*qinv*qg[d^1];
    const float krh = (d&1) ? ko : -ko;
    const float qrh = (d&1) ? qo : -qo;
    kn = kn*c + krh*sn;
    qn = qn*c + qrh*sn;
  }
  Kb[((size_t)hd*2304 + row)*128 + d] = f2b(kn);
  if (doq){
    const int qrow = row<1536 ? row : row-512;
    Q[((size_t)hd*1792 + qrow)*128 + d] = f2b(qn);
  }
}

// ---------------- V transpose ----------------
__global__ void v_transpose(const u16* __restrict__ h, u16* __restrict__ VT){
  __shared__ u16 Ls[32][33];
  const int tx = threadIdx.x, ty = threadIdx.y;  // (32,8)
  const int l0 = blockIdx.x*32, d0 = blockIdx.y*32, hd = blockIdx.z;
  #pragma unroll
  for (int r=0;r<4;r++)
    Ls[ty+r*8][tx] = h[(size_t)(l0+ty+r*8)*21504 + 6144 + hd*128 + d0 + tx];
  __syncthreads();
  #pragma unroll
  for (int r=0;r<4;r++)
    VT[((size_t)hd*128 + d0+ty+r*8)*2304 + l0 + tx] = Ls[tx][ty+r*8];
}

// ---------------- 128x128 2-barrier GEMM (small shapes; EPI 6 = f32 split-K partial) ----------------
template<int EPI>
__global__ __launch_bounds__(256)
void gemm_bt(const u16* __restrict__ A, const u16* __restrict__ Bt,
             const float* __restrict__ bias, void* __restrict__ Cv,
             int K, int ldA, int ldB, int ldC,
             long long sA, long long sB, long long sC)
{
  __shared__ u16 As[128*32];
  __shared__ u16 Bs[128*32];
  const int t = threadIdx.x;
  const int w = t>>6, lane = t&63;
  const int bm = blockIdx.y, bn = blockIdx.x, bz = blockIdx.z;
  const u16* Ab = A + (size_t)((long long)bz*sA) + (size_t)bm*128*ldA;
  const u16* Bb = Bt + (size_t)((long long)bz*sB) + (size_t)bn*128*ldB;
  const int wm = w>>1, wn = w&1;
  const int lr = lane&15, lk = lane>>4;
  const int row0 = t>>2, kp0 = (t&3)*8;
  char* AsB = (char*)As; char* BsB = (char*)Bs;
  const int off0 = w*1024;
  const int off1 = 4096 + w*1024;
  f32x4 acc[4][4] = {};

  for (int kt = 0; kt < K; kt += 32){
    __syncthreads();
    gload_lds16(Ab + (size_t)row0*ldA + kt + kp0,      AsB + off0);
    gload_lds16(Ab + (size_t)(row0+64)*ldA + kt + kp0, AsB + off1);
    gload_lds16(Bb + (size_t)row0*ldB + kt + kp0,      BsB + off0);
    gload_lds16(Bb + (size_t)(row0+64)*ldB + kt + kp0, BsB + off1);
    __syncthreads();
    bf16x8 av[4], bv[4];
    #pragma unroll
    for (int i=0;i<4;i++) av[i] = *(const bf16x8*)(As + (wm*64+i*16+lr)*32 + lk*8);
    #pragma unroll
    for (int j=0;j<4;j++) bv[j] = *(const bf16x8*)(Bs + (wn*64+j*16+lr)*32 + lk*8);
    #pragma unroll
    for (int i=0;i<4;i++)
      #pragma unroll
      for (int j=0;j<4;j++)
        acc[i][j] = __builtin_amdgcn_mfma_f32_16x16x32_bf16(av[i], bv[j], acc[i][j], 0,0,0);
  }

  const int mBase = bm*128 + wm*64;
  const int nBase = bn*128 + wn*64;
  #pragma unroll
  for (int i=0;i<4;i++){
    #pragma unroll
    for (int j=0;j<4;j++){
      #pragma unroll
      for (int r=0;r<4;r++){
        const int m = mBase + i*16 + lk*4 + r;
        const int n = nBase + j*16 + lr;
        const float v = acc[i][j][r];
        const long long idx = (long long)bz*sC + (long long)m*ldC + n;
        if (EPI==6){
          ((float*)Cv)[idx] = v;
        } else {
          ((u16*)Cv)[idx] = f2b(v + bias[n]);
        }
      }
    }
  }
}

// ---------------- split-K combines for ref MLP ----------------
__global__ void comb_gelu(const float* __restrict__ P, const float* __restrict__ b,
                          u16* __restrict__ o){
  const size_t e = ((size_t)blockIdx.x*256 + threadIdx.x)*4;   // over 512*3072
  const int n = (int)(e % 3072);
  const size_t S = (size_t)512*3072;
  float4 a = *(const float4*)(P + e);
  #pragma unroll
  for (int c=1;c<6;c++){
    const float4 p = *(const float4*)(P + c*S + e);
    a.x+=p.x; a.y+=p.y; a.z+=p.z; a.w+=p.w;
  }
  const float4 bb = *(const float4*)(b + n);
  u16x4 ov;
  ov.x = f2b(gelu_f(a.x+bb.x)); ov.y = f2b(gelu_f(a.y+bb.y));
  ov.z = f2b(gelu_f(a.z+bb.z)); ov.w = f2b(gelu_f(a.w+bb.w));
  *(u16x4*)(o + e) = ov;
}
__global__ void comb_bias(const float* __restrict__ P, const float* __restrict__ b,
                          float* __restrict__ o){
  const size_t e = ((size_t)blockIdx.x*256 + threadIdx.x)*4;
  const int n = (int)(e % 3072);
  const size_t S = (size_t)512*3072;
  float4 a = *(const float4*)(P + e);
  #pragma unroll
  for (int c=1;c<6;c++){
    const float4 p = *(const float4*)(P + c*S + e);
    a.x+=p.x; a.y+=p.y; a.z+=p.z; a.w+=p.w;
  }
  const float4 bb = *(const float4*)(b + n);
  float4 ov; ov.x=a.x+bb.x; ov.y=a.y+bb.y; ov.z=a.z+bb.z; ov.w=a.w+bb.w;
  *(float4*)(o + e) = ov;
}

// ================= 256x256 GEMM, BK=32, 2 blocks/CU (T1+T2+T4+T5 + occupancy) =================
// LDS 64KB: 4 x 16KB tiles {s0A,s0B,s1A,s1B}. K-tile=32.
// LDS packing: two K=32 rows per 128B LDS row; slot(r,hi) = (((r&1)<<2)+hi) ^ ((r>>1)&7).
// Staging (2 gloads/thread/tile): prologue {A0,B0,B1}, vmcnt(2);
// tile t: phase A {read A q0,q1 + B; stage A(t+1)->snA}, phase B {read A q2,q3; stage B(t+2)->scB},
// tail vmcnt(2) (= B(t+2) in flight). All write-after-read separated by barriers.
// CEPI 0: C(bf16)=acc+bias; lin1 mlp tiles (gm==-1 && bn>=36) -> Cv2=out2 with gelu.
// CEPI 1: C(f32 at sk*sC)=acc (split-K partial).
#define G256_BAR()  __builtin_amdgcn_s_barrier()
#define G256_LGKM() do{ asm volatile("s_waitcnt lgkmcnt(0)" ::: "memory"); \
                        __builtin_amdgcn_sched_barrier(0); }while(0)
#define G256_VM2()  asm volatile("s_waitcnt vmcnt(2)" ::: "memory")
#define G256_VM0()  asm volatile("s_waitcnt vmcnt(0)" ::: "memory")

__device__ __forceinline__ void lin1_map(int tw, int& bm, int& bn){
  if (tw < 504){
    const int band = tw/252; const int rr = tw - band*252;
    bn = rr/3; bm = band*3 + (rr - bn*3);
  } else if (tw < 588){
    bm = 8; bn = tw - 504;
  } else {
    const int rem = tw - 588;
    bm = 6 + (rem&1); bn = 12 + (rem>>1);
  }
}

// frag read: matrix base S, output row r, kslice lk
#define G256_ARD(S, r) (*(const bf16x8*)((S) + (((r)>>1)<<7) + \
    (((((((r)&1)<<2)) + lk) ^ (((r)>>1)&7))<<4)))

template<int CEPI>
__global__ __launch_bounds__(512,4)
void gemm256(const u16* __restrict__ A, const u16* __restrict__ Bt,
             const float* __restrict__ bias, void* __restrict__ Cv, void* __restrict__ Cv2,
             int Kc, int ld, int ldC, int nbn, int ntile, long long sC, int nwg, int gm)
{
  __shared__ char smem[65536];
  const int t = threadIdx.x;
  const int wid = t>>6, lane = t&63;
  const int lr = lane&15, lk = lane>>4;
  const int wm = wid>>2, wn = wid&3;

  // bijective XCD swizzle (m204)
  const int orig = blockIdx.x;
  const int q8 = nwg>>3, r8 = nwg&7;
  const int xcd = orig&7, jj = orig>>3;
  const int wg = (xcd<r8 ? xcd*(q8+1) : r8*(q8+1) + (xcd-r8)*q8) + jj;
  int sk, bm, bn;
  if (gm == -1){
    sk = 0; lin1_map(wg, bm, bn);
  } else if (gm > 0){
    const int band = wg / (gm*nbn);
    const int rr = wg - band*(gm*nbn);
    bn = rr / gm;
    bm = band*gm + (rr - bn*gm);
    sk = 0;
  } else {
    sk = wg / ntile;
    const int rem = wg - sk*ntile;
    bm = rem / nbn; bn = rem % nbn;
  }

  const u16* Agl = A  + (size_t)bm*256*ld + (size_t)sk*Kc;
  const u16* Bgl = Bt + (size_t)bn*256*ld + (size_t)sk*Kc;
  const int NT = Kc>>5;

  // staging source offsets for this thread's two dest slots (d, d+512).
  // dest slot d: lds row'=d>>3, slot s=d&7; logical sl=s^(row'&7);
  // global row r=row'*2+(sl>>2), kcol=(sl&3)*8.
  const int d0 = wid*64 + lane;
  size_t so0, so1;
  {
    int rp = d0>>3, s = d0&7, sl = s ^ (rp&7);
    so0 = (size_t)(rp*2 + (sl>>2))*ld + (size_t)((sl&3)<<3);
    int d1 = d0 + 512;
    rp = d1>>3; s = d1&7; sl = s ^ (rp&7);
    so1 = (size_t)(rp*2 + (sl>>2))*ld + (size_t)((sl&3)<<3);
  }

  char* s0A = smem;
  char* s0B = smem + 16384;
  char* s1A = smem + 32768;
  char* s1B = smem + 49152;

  f32x4 acc[8][4] = {};
  bf16x8 bv[4];

  auto STAGE = [&](const u16* g, int kt, char* ldsMat){
    gload_lds16(g + so0 + kt, ldsMat + wid*1024);
    gload_lds16(g + so1 + kt, ldsMat + 8192 + wid*1024);
  };

  // ---- prologue: A(0)->s0A, B(0)->s0B, B(1)->s1B; leave B(1) in flight ----
  STAGE(Agl, 0, s0A);
  STAGE(Bgl, 0, s0B);
  STAGE(Bgl, 32, s1B);
  G256_VM2();
  G256_BAR();

  for (int tt = 0; tt < NT; ++tt){
    char* cA = (tt&1) ? s1A : s0A;
    char* cB = (tt&1) ? s1B : s0B;
    char* nA = (tt&1) ? s0A : s1A;
    const bool stA = (tt+1) < NT, stB = (tt+2) < NT;
    const int k1 = (tt+1)<<5, k2 = (tt+2)<<5;

    // ---- phase A: quadrants 0,1 ----
    {
      const int rb = wm*128 + lr;
      bf16x8 a00 = G256_ARD(cA, rb);
      bf16x8 a01 = G256_ARD(cA, rb+16);
      bf16x8 a10 = G256_ARD(cA, rb+32);
      bf16x8 a11 = G256_ARD(cA, rb+48);
      const int rbB = wn*64 + lr;
      bv[0] = G256_ARD(cB, rbB);
      bv[1] = G256_ARD(cB, rbB+16);
      bv[2] = G256_ARD(cB, rbB+32);
      bv[3] = G256_ARD(cB, rbB+48);
      if (stA) STAGE(Agl, k1, nA);
      G256_BAR();
      G256_LGKM();
      __builtin_amdgcn_s_setprio(1);
      #pragma unroll
      for (int j=0;j<4;j++){
        acc[0][j] = __builtin_amdgcn_mfma_f32_16x16x32_bf16(a00, bv[j], acc[0][j], 0,0,0);
        acc[1][j] = __builtin_amdgcn_mfma_f32_16x16x32_bf16(a01, bv[j], acc[1][j], 0,0,0);
        acc[2][j] = __builtin_amdgcn_mfma_f32_16x16x32_bf16(a10, bv[j], acc[2][j], 0,0,0);
        acc[3][j] = __builtin_amdgcn_mfma_f32_16x16x32_bf16(a11, bv[j], acc[3][j], 0,0,0);
      }
      __builtin_amdgcn_s_setprio(0);
      G256_BAR();
    }
    // ---- phase B: quadrants 2,3 ----
    {
      const int rb = wm*128 + 64 + lr;
      bf16x8 a20 = G256_ARD(cA, rb);
      bf16x8 a21 = G256_ARD(cA, rb+16);
      bf16x8 a30 = G256_ARD(cA, rb+32);
      bf16x8 a31 = G256_ARD(cA, rb+48);
      if (stB) STAGE(Bgl, k2, cB);
      G256_BAR();
      G256_LGKM();
      __builtin_amdgcn_s_setprio(1);
      #pragma unroll
      for (int j=0;j<4;j++){
        acc[4][j] = __builtin_amdgcn_mfma_f32_16x16x32_bf16(a20, bv[j], acc[4][j], 0,0,0);
        acc[5][j] = __builtin_amdgcn_mfma_f32_16x16x32_bf16(a21, bv[j], acc[5][j], 0,0,0);
        acc[6][j] = __builtin_amdgcn_mfma_f32_16x16x32_bf16(a30, bv[j], acc[6][j], 0,0,0);
        acc[7][j] = __builtin_amdgcn_mfma_f32_16x16x32_bf16(a31, bv[j], acc[7][j], 0,0,0);
      }
      __builtin_amdgcn_s_setprio(0);
      if (stB)      { G256_VM2(); }
      else if (stA) { G256_VM0(); }
      G256_BAR();
    }
  }

  // ---- epilogue (acc layout unchanged: acc[fi], fi=0..7 over M; n = wn*64 + j*16 + lr) ----
  const int mB = bm*256 + wm*128 + lk*4;
  const int nB = bn*256 + wn*64 + lr;
  if (CEPI==0 && gm==-1 && bn >= 36){
    const int mq = (bm <= 5) ? mB : (mB - 512);
    #pragma unroll
    for (int fi=0; fi<8; fi++){
      #pragma unroll
      for (int j=0; j<4; j++){
        const int n = nB + j*16;
        const float bb = bias[n];
        #pragma unroll
        for (int r=0;r<4;r++){
          ((u16*)Cv2)[(size_t)(mq + fi*16 + r)*15360 + (n - 6144)] = f2b(gelu_f(acc[fi][j][r] + bb));
        }
      }
    }
  } else {
    #pragma unroll
    for (int fi=0; fi<8; fi++){
      #pragma unroll
      for (int j=0; j<4; j++){
        const int n = nB + j*16;
        const float bb = (CEPI==0) ? bias[n] : 0.f;
        #pragma unroll
        for (int r=0;r<4;r++){
          const int m = mB + fi*16 + r;
          if (CEPI==0){
            ((u16*)Cv)[(size_t)m*ldC + n] = f2b(acc[fi][j][r] + bb);
          } else {
            ((float*)Cv)[(size_t)sk*sC + (size_t)m*ldC + n] = acc[fi][j][r];
          }
        }
      }
    }
  }
}

// ================= flash attention (80 KB LDS + VGPR<=128 -> 2 blocks/CU) =================
__global__ __launch_bounds__(512,4)
void flash_attn(const u16* __restrict__ Qb, const u16* __restrict__ Kb,
                const u16* __restrict__ VT, const int* __restrict__ tmask,
                u16* __restrict__ out2)
{
  __shared__ __attribute__((aligned(16))) char smf[81920];
  char* Ks0 = smf;            // 2 x [64][128] = 32 KB
  char* Vs0 = smf + 32768;    // 2 x [128 d][64 k] = 32 KB (Q temp at start)
  char* Ps  = smf + 65536;    // [128 q][64 k] = 16 KB
  const int t = threadIdx.x, wid = t>>6, lane = t&63;
  const int lr = lane&15, hi = lane>>4;
  const int head = blockIdx.y, qt = blockIdx.x;
  const int q0 = qt*128;
  const u16* Qg = Qb + ((size_t)head*1792 + q0)*128;
  const u16* Kg = Kb + (size_t)head*2304*128;
  const u16* Vg = VT + (size_t)head*128*2304;
  const float SCALE = 0.08838834764831845f;

  u32 kbits = 0;
  #pragma unroll
  for (int i=0;i<16;i++) kbits |= (u32)(tmask[i*16 + lr] != 0) << i;
  int fqr[4];
  #pragma unroll
  for (int r=0;r<4;r++){
    const int q = q0 + wid*16 + hi*4 + r;
    fqr[r] = (q < 1536) ? 1 : (tmask[q-1536] != 0);
  }

  // ---- stage Q (temp in Vs0) + K tile 0 ----
  #pragma unroll
  for (int c=0;c<4;c++){
    const int s = c*512 + wid*64 + lane;
    const int row = s>>4, dsl = s&15;
    gload_lds16(Qg + (size_t)row*128 + ((dsl ^ (row&7))<<3),
                Vs0 + (size_t)(c*512 + wid*64)*16);
  }
  #pragma unroll
  for (int c=0;c<2;c++){
    const int s = c*512 + wid*64 + lane;
    const int row = s>>4, dsl = s&15;
    gload_lds16(Kg + (size_t)row*128 + ((dsl ^ (row&7))<<3),
                Ks0 + (size_t)(c*512 + wid*64)*16);
  }
  asm volatile("s_waitcnt vmcnt(0)" ::: "memory");
  __syncthreads();

  // hoist Q A-frags from Vs0 (temp)
  bf16x8 av[4];
  {
    const int row = wid*16 + lr;
    #pragma unroll
    for (int ks=0;ks<4;ks++)
      av[ks] = *(const bf16x8*)(Vs0 + row*256 + (((ks*4+hi) ^ (row&7))<<4));
  }
  asm volatile("s_waitcnt lgkmcnt(0)" ::: "memory");
  __builtin_amdgcn_sched_barrier(0);
  __syncthreads();

  // ---- stage V tile 0 (overwrites Q temp) ----
  #pragma unroll
  for (int c=0;c<2;c++){
    const int s = c*512 + wid*64 + lane;
    const int row = s>>3, dsl = s&7;
    gload_lds16(Vg + (size_t)row*2304 + ((dsl ^ (row&7))<<3),
                Vs0 + (size_t)(c*512 + wid*64)*16);
  }
  asm volatile("s_waitcnt vmcnt(0)" ::: "memory");
  __syncthreads();

  f32x4 acc[8] = {};
  float m_[4], l_[4];
  #pragma unroll
  for (int r=0;r<4;r++){ m_[r] = -3e38f; l_[r] = 0.f; }

  for (int kt = 0; kt < 36; ++kt){
    char* Kc = Ks0 + (kt&1)*16384;
    char* Vc = Vs0 + (kt&1)*16384;
    if (kt+1 < 36){
      char* Kn = Ks0 + ((kt+1)&1)*16384;
      char* Vn = Vs0 + ((kt+1)&1)*16384;
      #pragma unroll
      for (int c=0;c<2;c++){
        const int s = c*512 + wid*64 + lane;
        { const int row = s>>4, dsl = s&15;
          gload_lds16(Kg + (size_t)((kt+1)*64 + row)*128 + ((dsl ^ (row&7))<<3),
                      Kn + (size_t)(c*512 + wid*64)*16); }
        { const int row = s>>3, dsl = s&7;
          gload_lds16(Vg + (size_t)row*2304 + (kt+1)*64 + ((dsl ^ (row&7))<<3),
                      Vn + (size_t)(c*512 + wid*64)*16); }
      }
    }
    f32x4 sacc[4] = {};
    #pragma unroll
    for (int ks=0;ks<4;ks++){
      #pragma unroll
      for (int j=0;j<4;j++){
        const int row = j*16 + lr;
        bf16x8 bk = *(const bf16x8*)(Kc + row*256 + (((ks*4+hi) ^ (row&7))<<4));
        sacc[j] = __builtin_amdgcn_mfma_f32_16x16x32_bf16(av[ks], bk, sacc[j], 0,0,0);
      }
    }
    int gkj[4];
    #pragma unroll
    for (int j=0;j<4;j++)
      gkj[j] = (kt < 32) ? 1 : (int)((kbits >> ((kt-32)*4 + j)) & 1u);
    float p[4][4]; bool alw[4][4];
    float mt[4] = {-3e38f,-3e38f,-3e38f,-3e38f};
    #pragma unroll
    for (int j=0;j<4;j++){
      #pragma unroll
      for (int r=0;r<4;r++){
        const float s = sacc[j][r]*SCALE;
        const bool a = (fqr[r] == gkj[j]);
        alw[j][r] = a; p[j][r] = s;
        if (a) mt[r] = fmaxf(mt[r], s);
      }
    }
    #pragma unroll
    for (int r=0;r<4;r++){
      #pragma unroll
      for (int o=1;o<16;o<<=1) mt[r] = fmaxf(mt[r], __shfl_xor(mt[r], o, 64));
      const float nm = fmaxf(m_[r], mt[r]);
      const float cr = __expf(m_[r] - nm);
      m_[r] = nm;
      l_[r] *= cr;
      #pragma unroll
      for (int jp=0;jp<8;jp++) acc[jp][r] *= cr;
    }
    float rs[4] = {0.f,0.f,0.f,0.f};
    #pragma unroll
    for (int j=0;j<4;j++){
      #pragma unroll
      for (int r=0;r<4;r++){
        const float pv = alw[j][r] ? __expf(p[j][r] - m_[r]) : 0.f;
        p[j][r] = pv; rs[r] += pv;
      }
    }
    #pragma unroll
    for (int r=0;r<4;r++){
      #pragma unroll
      for (int o=1;o<16;o<<=1) rs[r] += __shfl_xor(rs[r], o, 64);
      l_[r] += rs[r];
    }
    #pragma unroll
    for (int j=0;j<4;j++){
      #pragma unroll
      for (int r=0;r<4;r++){
        const int q = wid*16 + hi*4 + r;
        const int k = j*16 + lr;
        *(u16*)(Ps + q*128 + (((k>>3) ^ (q&7))<<4) + (k&7)*2) = f2b(p[j][r]);
      }
    }
    asm volatile("s_waitcnt lgkmcnt(0)" ::: "memory");
    __builtin_amdgcn_sched_barrier(0);
    bf16x8 pa[2];
    {
      const int row = wid*16 + lr;
      #pragma unroll
      for (int ks2=0;ks2<2;ks2++)
        pa[ks2] = *(const bf16x8*)(Ps + row*128 + (((ks2*4+hi) ^ (row&7))<<4));
    }
    #pragma unroll
    for (int ks2=0;ks2<2;ks2++){
      #pragma unroll
      for (int jp=0;jp<8;jp++){
        const int row = jp*16 + lr;
        bf16x8 bvv = *(const bf16x8*)(Vc + row*128 + (((ks2*4+hi) ^ (row&7))<<4));
        acc[jp] = __builtin_amdgcn_mfma_f32_16x16x32_bf16(pa[ks2], bvv, acc[jp], 0,0,0);
      }
    }
    asm volatile("s_waitcnt vmcnt(0)" ::: "memory");
    __syncthreads();
  }

  float inv[4];
  #pragma unroll
  for (int r=0;r<4;r++) inv[r] = 1.f/l_[r];
  #pragma unroll
  for (int jp=0;jp<8;jp++){
    #pragma unroll
    for (int r=0;r<4;r++){
      const size_t q = q0 + wid*16 + hi*4 + r;
      out2[q*15360 + head*128 + jp*16 + lr] = f2b(acc[jp][r]*inv[r]);
    }
  }
}

// ---------------- lin2 finish: out = x + (p0+p1+p2+bias)*gate ----------------
__global__ void lin2_fin(const float* __restrict__ P, const float* __restrict__ x,
                         const float* __restrict__ bias, const float* __restrict__ gate,
                         float* __restrict__ out){
  const size_t e = ((size_t)blockIdx.x*256 + threadIdx.x)*4;   // over 1792*3072
  const int n = (int)(e % 3072);
  const size_t S = (size_t)1792*3072;
  float4 a = *(const float4*)(P + e);
  #pragma unroll
  for (int c=1;c<3;c++){
    const float4 p = *(const float4*)(P + c*S + e);
    a.x+=p.x; a.y+=p.y; a.z+=p.z; a.w+=p.w;
  }
  const float4 bb = *(const float4*)(bias + n);
  const float4 gg = *(const float4*)(gate + n);
  const float4 xv = *(const float4*)(x + e);
  float4 o;
  o.x = xv.x + (a.x+bb.x)*gg.x;
  o.y = xv.y + (a.y+bb.y)*gg.y;
  o.z = xv.z + (a.z+bb.z)*gg.z;
  o.w = xv.w + (a.w+bb.w)*gg.w;
  *(float4*)(out + e) = o;
}

// ---------------- host orchestration ----------------
extern "C" void kernel_launch(void* const* d_in, const int* in_sizes, int n_in,
                              void* d_out, int out_size, void* d_ws, size_t ws_size,
                              hipStream_t stream)
{
  (void)in_sizes; (void)n_in; (void)out_size; (void)ws_size;
  const float* x     = (const float*)d_in[0];
  const float* vec   = (const float*)d_in[1];
  const float* ref   = (const float*)d_in[2];
  const float* cosb  = (const float*)d_in[3];
  const float* sinb  = (const float*)d_in[4];
  const float* mod_w = (const float*)d_in[5];
  const float* mod_b = (const float*)d_in[6];
  const float* rf1_w = (const float*)d_in[7];
  const float* rf1_b = (const float*)d_in[8];
  const float* rf2_w = (const float*)d_in[9];
  const float* rf2_b = (const float*)d_in[10];
  const float* rln_g = (const float*)d_in[11];
  const float* rln_b = (const float*)d_in[12];
  const float* lin1_w= (const float*)d_in[13];
  const float* lin1_b= (const float*)d_in[14];
  const float* q_g   = (const float*)d_in[15];
  const float* k_g   = (const float*)d_in[16];
  const float* lin2_w= (const float*)d_in[17];
  const float* lin2_b= (const float*)d_in[18];
  const int*   tmask = (const int*)d_in[19];
  float* out = (float*)d_out;
  char* ws = (char*)d_ws;

  float* modp = (float*)(ws + 0);                    // 9216 f32
  float* part = (float*)(ws + 36864);                // 24*9216 f32
  u16*  w2t   = (u16*)(ws + 921600);                 // 3072 x 15360
  u16*  Qb    = (u16*)(ws + 95293440ll);             // 24 x 1792 x 128
  u16*  Kb    = (u16*)(ws + 106303488ll);            // 24 x 2304 x 128
  u16*  VT    = (u16*)(ws + 120459264ll);            // 24 x 128 x 2304
  u16*  out2  = (u16*)(ws + 134615040ll);            // 1792 x 15360
  u16*  w1t   = (u16*)(ws + 189665280ll);            // 21504 x 3072
  u16*  xc    = (u16*)(ws + 321785856ll);            // 2304 x 3072
  u16*  rf1t  = (u16*)(ws + 335941632ll);            // 3072 x 3072
  u16*  rf2t  = (u16*)(ws + 354816000ll);            // 3072 x 3072
  u16*  refb  = (u16*)(ws + 373690368ll);            // 512 x 3072
  u16*  tb    = (u16*)(ws + 376836096ll);            // 512 x 3072
  float* rtmp = (float*)(ws + 379981824ll);          // 512 x 3072 f32
  float* rp   = (float*)(ws + 386273280ll);          // 6 x 512 x 3072 f32 (pre-lin1 scratch)
  u16*  hbuf  = (u16*)(ws + 335941632ll);            // 2304 x 21504 (qkv cols only)
  float* p2b  = (float*)(ws + 189665280ll);          // 3 x 1792 x 3072 f32 (alias w1t/xc region)

  // 1) modulation GEMV
  modv_part<<<dim3(36,24),256,0,stream>>>(vec, mod_w, part);
  modv_reduce<<<36,256,0,stream>>>(part, mod_b, modp);
  // 2) weight conversions (64x64 tile, float4/u16x4)
  convT<<<dim3(48,48),  256,0,stream>>>(rf1_w, rf1t, 3072, 3072);
  convT<<<dim3(48,48),  256,0,stream>>>(rf2_w, rf2t, 3072, 3072);
  convT<<<dim3(336,48), 256,0,stream>>>(lin1_w, w1t, 3072, 21504);
  convT<<<dim3(48,240), 256,0,stream>>>(lin2_w, w2t, 15360, 3072);
  convertF2B<<<1536,256,0,stream>>>(ref, refb);
  // 3) LN + modulate
  ln_modulate<<<1792,256,0,stream>>>(x, modp, xc);
  // 4) ref MLP (split-K=6) -> LN
  gemm_bt<6><<<dim3(24,4,6),256,0,stream>>>(refb, rf1t, nullptr, rp, 512, 3072,3072,3072,
                                            512,512, (long long)512*3072);
  comb_gelu<<<1536,256,0,stream>>>(rp, rf1_b, tb);
  gemm_bt<6><<<dim3(24,4,6),256,0,stream>>>(tb, rf2t, nullptr, rp, 512, 3072,3072,3072,
                                            512,512, (long long)512*3072);
  comb_bias<<<1536,256,0,stream>>>(rp, rf2_b, rtmp);
  ln_ref<<<512,256,0,stream>>>(rtmp, rln_g, rln_b, xc);
  // 5) lin1 sparse map, BK=32 2-blocks/CU: 636 blocks; qkv -> hbuf, mlp gelu -> out2
  gemm256<0><<<636,512,0,stream>>>(xc, w1t, lin1_b, hbuf, out2, 3072, 3072, 21504, 84, 636, 0, 636, -1);
  // 6) q/k norm + rope, V transpose
  qk_prep<<<dim3(2304,24),128,0,stream>>>(hbuf, q_g, k_g, cosb, sinb, Qb, Kb);
  v_transpose<<<dim3(72,4,24),dim3(32,8),0,stream>>>(hbuf, VT);
  // 7) flash attention -> out2[:, :3072]
  flash_attn<<<dim3(14,24),512,0,stream>>>(Qb, Kb, VT, tmask, out2);
  // 8) lin2 split-K=3, BK=32: M=1792 (7 tiles), N=3072 (12 tiles), Kc=5120 (NT=160), 252 blocks
  gemm256<1><<<252,512,0,stream>>>(out2, w2t, nullptr, p2b, nullptr, 5120, 15360, 3072, 12, 84,
                                   (long long)1792*3072, 252, 0);
  lin2_fin<<<5376,256,0,stream>>>(p2b, x, lin2_b, modp + 6144, out);
}

// Round 16
// 866.035 us; speedup vs baseline: 4.9351x; 4.9351x over previous
//
#include <hip/hip_runtime.h>
#include <cstdint>
#include <cstddef>

typedef unsigned short u16;
typedef unsigned int   u32;
typedef __bf16 bf16_t;
typedef bf16_t bf16x8 __attribute__((ext_vector_type(8)));
typedef float  f32x4  __attribute__((ext_vector_type(4)));
typedef u16    u16x4  __attribute__((ext_vector_type(4)));

// ---- problem constants ----
// H=3072 NH=24 HD=128 MLP_D=12288 IMG=1536 REF=512 TXT=256
// LQ = 1792, L2 = 2304, N1 = 21504, K2 = 15360

__device__ __forceinline__ float b2f(u16 b){ u32 u=((u32)b)<<16; float f; __builtin_memcpy(&f,&u,4); return f; }
__device__ __forceinline__ u16 f2b(float f){ u32 u; __builtin_memcpy(&u,&f,4); u = u + 0x7fffu + ((u>>16)&1u); return (u16)(u>>16); }
// gelu(x) = x * sigmoid(1.5957691*(x+0.044715x^3))
__device__ __forceinline__ float gelu_f(float x){
  const float u2 = 1.5957691216057308f*(x + 0.044715f*x*x*x);
  return x/(1.f + __expf(-u2));
}

__device__ __forceinline__ void gload_lds16(const void* g, void* l){
  __builtin_amdgcn_global_load_lds((const __attribute__((address_space(1))) void*)g,
                                   (__attribute__((address_space(3))) void*)l, 16, 0, 0);
}

template<int NW, bool MX>
__device__ __forceinline__ float bred(float v, float* red){
  #pragma unroll
  for (int o=32;o;o>>=1){ float u=__shfl_down(v,o,64); v = MX? fmaxf(v,u) : v+u; }
  const int t = threadIdx.x;
  if ((t&63)==0) red[t>>6]=v;
  __syncthreads();
  float r = red[0];
  #pragma unroll
  for (int i=1;i<NW;i++) r = MX? fmaxf(r,red[i]) : r+red[i];
  __syncthreads();
  return r;
}

// ---------------- mod GEMV ----------------
__global__ void modv_part(const float* __restrict__ vec, const float* __restrict__ W,
                          float* __restrict__ part){
  __shared__ float s[128];
  const int t = threadIdx.x;
  const int j = blockIdx.x*256 + t;
  const int i0 = blockIdx.y*128;
  if (t < 128){ float v = vec[i0+t]; s[t] = v/(1.f+__expf(-v)); }
  __syncthreads();
  float acc = 0.f;
  #pragma unroll 8
  for (int i=0;i<128;i++) acc += s[i]*W[(size_t)(i0+i)*9216 + j];
  part[(size_t)blockIdx.y*9216 + j] = acc;
}
__global__ void modv_reduce(const float* __restrict__ part, const float* __restrict__ mb,
                            float* __restrict__ modp){
  const int j = blockIdx.x*256 + threadIdx.x;
  float a = mb[j];
  #pragma unroll
  for (int c=0;c<24;c++) a += part[(size_t)c*9216 + j];
  modp[j] = a;
}

// ---------------- fp32 (K x N) -> bf16 transposed (N x K), 64x64 tile ----------------
__global__ __launch_bounds__(256)
void convT(const float* __restrict__ W, u16* __restrict__ Wt, int Kd, int Nd){
  __shared__ float Ls[64][65];
  const int t = threadIdx.x;
  const int n0 = blockIdx.x*64, k0 = blockIdx.y*64;
  const int tr = t>>4;        // 0..15
  const int tc = (t&15)*4;    // 0,4,...,60
  #pragma unroll
  for (int p=0;p<4;p++){
    const int kk = tr + p*16;
    const float4 v = *(const float4*)(W + (size_t)(k0+kk)*Nd + n0 + tc);
    Ls[kk][tc+0]=v.x; Ls[kk][tc+1]=v.y; Ls[kk][tc+2]=v.z; Ls[kk][tc+3]=v.w;
  }
  __syncthreads();
  #pragma unroll
  for (int p=0;p<4;p++){
    const int nn = tr + p*16;
    u16x4 o;
    o.x = f2b(Ls[tc+0][nn]); o.y = f2b(Ls[tc+1][nn]);
    o.z = f2b(Ls[tc+2][nn]); o.w = f2b(Ls[tc+3][nn]);
    *(u16x4*)(Wt + (size_t)(n0+nn)*Kd + k0 + tc) = o;
  }
}

__global__ void convertF2B(const float* __restrict__ src, u16* __restrict__ dst){
  const size_t i = ((size_t)blockIdx.x*256 + threadIdx.x)*4;
  const float4 v = *(const float4*)(src+i);
  u16x4 o; o.x=f2b(v.x); o.y=f2b(v.y); o.z=f2b(v.z); o.w=f2b(v.w);
  *(u16x4*)(dst+i) = o;
}

// ---------------- LN(x)*(1+scale)+shift -> xc (bf16) ----------------
__global__ void ln_modulate(const float* __restrict__ x, const float* __restrict__ modp,
                            u16* __restrict__ xc){
  __shared__ float red[4];
  const int row = blockIdx.x, t = threadIdx.x;
  const float* xr = x + (size_t)row*3072;
  float4 v[3]; float s=0.f, ss=0.f;
  #pragma unroll
  for (int k=0;k<3;k++){
    v[k] = *(const float4*)(xr + t*4 + k*1024);
    s  += v[k].x+v[k].y+v[k].z+v[k].w;
    ss += v[k].x*v[k].x+v[k].y*v[k].y+v[k].z*v[k].z+v[k].w*v[k].w;
  }
  s  = bred<4,false>(s, red);
  ss = bred<4,false>(ss, red);
  const float mean = s*(1.f/3072.f);
  const float inv = rsqrtf(ss*(1.f/3072.f)-mean*mean + 1e-6f);
  const int orow = row<1536 ? row : row+512;
  u16* o = xc + (size_t)orow*3072;
  const float* shiftp = modp; const float* scalep = modp+3072;
  #pragma unroll
  for (int k=0;k<3;k++){
    const int j = t*4 + k*1024;
    const float4 sc = *(const float4*)(scalep+j);
    const float4 sh = *(const float4*)(shiftp+j);
    u16x4 ov;
    ov.x = f2b((v[k].x-mean)*inv*(1.f+sc.x)+sh.x);
    ov.y = f2b((v[k].y-mean)*inv*(1.f+sc.y)+sh.y);
    ov.z = f2b((v[k].z-mean)*inv*(1.f+sc.z)+sh.z);
    ov.w = f2b((v[k].w-mean)*inv*(1.f+sc.w)+sh.w);
    *(u16x4*)(o+j) = ov;
  }
}

// ---------------- LN(r)*g+b -> xc rows [1536,2048) ----------------
__global__ void ln_ref(const float* __restrict__ rt, const float* __restrict__ g,
                       const float* __restrict__ b, u16* __restrict__ xc){
  __shared__ float red[4];
  const int row = blockIdx.x, t = threadIdx.x;
  const float* xr = rt + (size_t)row*3072;
  float4 v[3]; float s=0.f, ss=0.f;
  #pragma unroll
  for (int k=0;k<3;k++){
    v[k] = *(const float4*)(xr + t*4 + k*1024);
    s  += v[k].x+v[k].y+v[k].z+v[k].w;
    ss += v[k].x*v[k].x+v[k].y*v[k].y+v[k].z*v[k].z+v[k].w*v[k].w;
  }
  s  = bred<4,false>(s, red);
  ss = bred<4,false>(ss, red);
  const float mean = s*(1.f/3072.f);
  const float inv = rsqrtf(ss*(1.f/3072.f)-mean*mean + 1e-6f);
  u16* o = xc + (size_t)(1536+row)*3072;
  #pragma unroll
  for (int k=0;k<3;k++){
    const int j = t*4 + k*1024;
    const float4 gv = *(const float4*)(g+j);
    const float4 bv = *(const float4*)(b+j);
    u16x4 ov;
    ov.x = f2b((v[k].x-mean)*inv*gv.x+bv.x);
    ov.y = f2b((v[k].y-mean)*inv*gv.y+bv.y);
    ov.z = f2b((v[k].z-mean)*inv*gv.z+bv.z);
    ov.w = f2b((v[k].w-mean)*inv*gv.w+bv.w);
    *(u16x4*)(o+j) = ov;
  }
}

// ---------------- RMS-norm + RoPE on q,k from h ----------------
__global__ void qk_prep(const u16* __restrict__ h, const float* __restrict__ qg,
                        const float* __restrict__ kg, const float* __restrict__ cosb,
                        const float* __restrict__ sinb, u16* __restrict__ Q,
                        u16* __restrict__ Kb){
  __shared__ float red[4];
  const int row = blockIdx.x, hd = blockIdx.y, d = threadIdx.x; // 128 threads
  const u16* hr = h + (size_t)row*21504;
  const float kv = b2f(hr[3072 + hd*128 + d]);
  const bool doq = (row < 1536) || (row >= 2048);
  const float qv = doq ? b2f(hr[hd*128 + d]) : 0.f;
  float a = kv*kv, b = qv*qv;
  #pragma unroll
  for (int o=32;o;o>>=1){ a += __shfl_down(a,o,64); b += __shfl_down(b,o,64); }
  if ((d&63)==0){ red[(d>>6)*2] = a; red[(d>>6)*2+1] = b; }
  __syncthreads();
  const float kinv = rsqrtf((red[0]+red[2])*(1.f/128.f) + 1e-6f);
  const float qinv = rsqrtf((red[1]+red[3])*(1.f/128.f) + 1e-6f);
  float kn = kv*kinv*kg[d];
  float qn = qv*qinv*qg[d];
  if (row < 1536){
    const float c  = cosb[row*128 + d];
    const float sn = sinb[row*128 + d];
    const float ko = b2f(hr[3072 + hd*128 + (d^1)])*kinv*kg[d^1];
    const float qo = b2f(hr[hd*128 + (d^1)])*qinv*qg[d^1];
    const float krh = (d&1) ? ko : -ko;
    const float qrh = (d&1) ? qo : -qo;
    kn = kn*c + krh*sn;
    qn = qn*c + qrh*sn;
  }
  Kb[((size_t)hd*2304 + row)*128 + d] = f2b(kn);
  if (doq){
    const int qrow = row<1536 ? row : row-512;
    Q[((size_t)hd*1792 + qrow)*128 + d] = f2b(qn);
  }
}

// ---------------- V transpose ----------------
__global__ void v_transpose(const u16* __restrict__ h, u16* __restrict__ VT){
  __shared__ u16 Ls[32][33];
  const int tx = threadIdx.x, ty = threadIdx.y;  // (32,8)
  const int l0 = blockIdx.x*32, d0 = blockIdx.y*32, hd = blockIdx.z;
  #pragma unroll
  for (int r=0;r<4;r++)
    Ls[ty+r*8][tx] = h[(size_t)(l0+ty+r*8)*21504 + 6144 + hd*128 + d0 + tx];
  __syncthreads();
  #pragma unroll
  for (int r=0;r<4;r++)
    VT[((size_t)hd*128 + d0+ty+r*8)*2304 + l0 + tx] = Ls[tx][ty+r*8];
}

// ---------------- 128x128 2-barrier GEMM (small shapes; EPI 6 = f32 split-K partial) ----------------
template<int EPI>
__global__ __launch_bounds__(256)
void gemm_bt(const u16* __restrict__ A, const u16* __restrict__ Bt,
             const float* __restrict__ bias, void* __restrict__ Cv,
             int K, int ldA, int ldB, int ldC,
             long long sA, long long sB, long long sC)
{
  __shared__ u16 As[128*32];
  __shared__ u16 Bs[128*32];
  const int t = threadIdx.x;
  const int w = t>>6, lane = t&63;
  const int bm = blockIdx.y, bn = blockIdx.x, bz = blockIdx.z;
  const u16* Ab = A + (size_t)((long long)bz*sA) + (size_t)bm*128*ldA;
  const u16* Bb = Bt + (size_t)((long long)bz*sB) + (size_t)bn*128*ldB;
  const int wm = w>>1, wn = w&1;
  const int lr = lane&15, lk = lane>>4;
  const int row0 = t>>2, kp0 = (t&3)*8;
  char* AsB = (char*)As; char* BsB = (char*)Bs;
  const int off0 = w*1024;
  const int off1 = 4096 + w*1024;
  f32x4 acc[4][4] = {};

  for (int kt = 0; kt < K; kt += 32){
    __syncthreads();
    gload_lds16(Ab + (size_t)row0*ldA + kt + kp0,      AsB + off0);
    gload_lds16(Ab + (size_t)(row0+64)*ldA + kt + kp0, AsB + off1);
    gload_lds16(Bb + (size_t)row0*ldB + kt + kp0,      BsB + off0);
    gload_lds16(Bb + (size_t)(row0+64)*ldB + kt + kp0, BsB + off1);
    __syncthreads();
    bf16x8 av[4], bv[4];
    #pragma unroll
    for (int i=0;i<4;i++) av[i] = *(const bf16x8*)(As + (wm*64+i*16+lr)*32 + lk*8);
    #pragma unroll
    for (int j=0;j<4;j++) bv[j] = *(const bf16x8*)(Bs + (wn*64+j*16+lr)*32 + lk*8);
    #pragma unroll
    for (int i=0;i<4;i++)
      #pragma unroll
      for (int j=0;j<4;j++)
        acc[i][j] = __builtin_amdgcn_mfma_f32_16x16x32_bf16(av[i], bv[j], acc[i][j], 0,0,0);
  }

  const int mBase = bm*128 + wm*64;
  const int nBase = bn*128 + wn*64;
  #pragma unroll
  for (int i=0;i<4;i++){
    #pragma unroll
    for (int j=0;j<4;j++){
      #pragma unroll
      for (int r=0;r<4;r++){
        const int m = mBase + i*16 + lk*4 + r;
        const int n = nBase + j*16 + lr;
        const float v = acc[i][j][r];
        const long long idx = (long long)bz*sC + (long long)m*ldC + n;
        if (EPI==6){
          ((float*)Cv)[idx] = v;
        } else {
          ((u16*)Cv)[idx] = f2b(v + bias[n]);
        }
      }
    }
  }
}

// ---------------- split-K combines for ref MLP ----------------
__global__ void comb_gelu(const float* __restrict__ P, const float* __restrict__ b,
                          u16* __restrict__ o){
  const size_t e = ((size_t)blockIdx.x*256 + threadIdx.x)*4;   // over 512*3072
  const int n = (int)(e % 3072);
  const size_t S = (size_t)512*3072;
  float4 a = *(const float4*)(P + e);
  #pragma unroll
  for (int c=1;c<6;c++){
    const float4 p = *(const float4*)(P + c*S + e);
    a.x+=p.x; a.y+=p.y; a.z+=p.z; a.w+=p.w;
  }
  const float4 bb = *(const float4*)(b + n);
  u16x4 ov;
  ov.x = f2b(gelu_f(a.x+bb.x)); ov.y = f2b(gelu_f(a.y+bb.y));
  ov.z = f2b(gelu_f(a.z+bb.z)); ov.w = f2b(gelu_f(a.w+bb.w));
  *(u16x4*)(o + e) = ov;
}
__global__ void comb_bias(const float* __restrict__ P, const float* __restrict__ b,
                          float* __restrict__ o){
  const size_t e = ((size_t)blockIdx.x*256 + threadIdx.x)*4;
  const int n = (int)(e % 3072);
  const size_t S = (size_t)512*3072;
  float4 a = *(const float4*)(P + e);
  #pragma unroll
  for (int c=1;c<6;c++){
    const float4 p = *(const float4*)(P + c*S + e);
    a.x+=p.x; a.y+=p.y; a.z+=p.z; a.w+=p.w;
  }
  const float4 bb = *(const float4*)(b + n);
  float4 ov; ov.x=a.x+bb.x; ov.y=a.y+bb.y; ov.z=a.z+bb.z; ov.w=a.w+bb.w;
  *(float4*)(o + e) = ov;
}

// ================= 256x256 GEMM, m201 8-phase schedule (T1+T2+T3+T4+T5) =================
// 2 K-tiles per iteration, 8 phases; counted vmcnt(4) only at phases 4 and 8.
// Staging ledger (tile tau -> slot tau&1):
//  P1: A(t+1)->s1A   P2: B0(t+2)->s0B  P3: B1(t+2)->s0B
//  P5: A0(t+2)->s0A  P6: A1(t+2)->s0A  P7: B0(t+3)->s1B  P8: B1(t+3)->s1B
// Region free-times: s0B after P1, s0A after P4, s1B after P5, s1A after P8. NT must be EVEN.
// CEPI 0: C(bf16)=acc+bias; lin1 mlp tiles (gm==-1 && bn>=36) -> Cv2=out2 with gelu.
// CEPI 1: C(f32 at sk*sC)=acc (split-K partial).
// gm>0: grouped bands; gm==0: split-K; gm==-1: lin1 sparse 636-tile map. All XCD-swizzled.
#define G256_BAR()  __builtin_amdgcn_s_barrier()
#define G256_LGKM() do{ asm volatile("s_waitcnt lgkmcnt(0)" ::: "memory"); \
                        __builtin_amdgcn_sched_barrier(0); }while(0)
#define G256_VM4()  asm volatile("s_waitcnt vmcnt(4)" ::: "memory")
#define G256_VM0()  asm volatile("s_waitcnt vmcnt(0)" ::: "memory")

__device__ __forceinline__ void lin1_map(int tw, int& bm, int& bn){
  if (tw < 504){
    const int band = tw/252; const int rr = tw - band*252;
    bn = rr/3; bm = band*3 + (rr - bn*3);
  } else if (tw < 588){
    bm = 8; bn = tw - 504;
  } else {
    const int rem = tw - 588;
    bm = 6 + (rem&1); bn = 12 + (rem>>1);
  }
}

template<int CEPI>
__global__ __launch_bounds__(512,2)
void gemm256(const u16* __restrict__ A, const u16* __restrict__ Bt,
             const float* __restrict__ bias, void* __restrict__ Cv, void* __restrict__ Cv2,
             int Kc, int ld, int ldC, int nbn, int ntile, long long sC, int nwg, int gm)
{
  __shared__ char smem[131072];
  const int t = threadIdx.x;
  const int wid = t>>6, lane = t&63;
  const int lr = lane&15, lk = lane>>4;
  const int wm = wid>>2, wn = wid&3;

  // bijective XCD swizzle (m204)
  const int orig = blockIdx.x;
  const int q8 = nwg>>3, r8 = nwg&7;
  const int xcd = orig&7, jj = orig>>3;
  const int wg = (xcd<r8 ? xcd*(q8+1) : r8*(q8+1) + (xcd-r8)*q8) + jj;
  int sk, bm, bn;
  if (gm == -1){
    sk = 0; lin1_map(wg, bm, bn);
  } else if (gm > 0){
    const int band = wg / (gm*nbn);
    const int rr = wg - band*(gm*nbn);
    bn = rr / gm;
    bm = band*gm + (rr - bn*gm);
    sk = 0;
  } else {
    sk = wg / ntile;
    const int rem = wg - sk*ntile;
    bm = rem / nbn; bn = rem % nbn;
  }

  const u16* Agl = A  + (size_t)bm*256*ld + (size_t)sk*Kc;
  const u16* Bgl = Bt + (size_t)bn*256*ld + (size_t)sk*Kc;
  const int NT = Kc>>6;     // even
  const int NI = NT>>1;

  // staging: dest idx d0 in [0,512): row sr=d0>>3, dest 16B-slot=d0&7;
  // global source slot = dest_slot ^ (sr&7) (inverse swizzle, rule 21).
  const int d0 = wid*64 + lane;
  const int sr = d0>>3;
  const size_t soff = (size_t)sr*ld + (size_t)(((d0&7)^(sr&7))<<3);
  // read-side swizzled 16B-slot byte offsets
  const int xsl0 = ((lk    ) ^ (lr&7))<<4;   // ks=0
  const int xsl1 = ((lk | 4) ^ (lr&7))<<4;   // ks=1

  char* s0A = smem;
  char* s0B = smem + 32768;
  char* s1A = smem + 65536;
  char* s1B = smem + 98304;

  f32x4 acc[8][4] = {};
  bf16x8 bv[4][2];

  auto STAGE = [&](const u16* g, int h, int kt, char* ldsMat){
    const u16* s0 = g + (size_t)(h*128)*ld + kt + soff;
    char* l0 = ldsMat + h*16384 + wid*1024;
    gload_lds16(s0, l0);
    gload_lds16(s0 + (size_t)64*ld, l0 + 8192);
  };

  // ---- prologue: A(0)->s0A, B(0)->s0B, B(1)->s1B; leave B(1) in flight ----
  STAGE(Agl, 0, 0, s0A);
  STAGE(Agl, 1, 0, s0A);
  STAGE(Bgl, 0, 0, s0B);
  STAGE(Bgl, 1, 0, s0B);
  STAGE(Bgl, 0, 64, s1B);
  STAGE(Bgl, 1, 64, s1B);
  G256_VM4();
  G256_BAR();

#define G256_PH(SA, Q, READB, SB, STG, TAILV)                                   \
  do{                                                                           \
    const char* ab = SA + (wm*128 + (Q)*32 + lr)*128;                           \
    bf16x8 a0 = *(const bf16x8*)(ab + xsl0);                                    \
    bf16x8 a1 = *(const bf16x8*)(ab + xsl1);                                    \
    bf16x8 a2 = *(const bf16x8*)(ab + 2048 + xsl0);                             \
    bf16x8 a3 = *(const bf16x8*)(ab + 2048 + xsl1);                             \
    if (READB){                                                                 \
      _Pragma("unroll")                                                         \
      for (int j=0;j<4;j++){                                                    \
        const char* bb = SB + (wn*64 + j*16 + lr)*128;                          \
        bv[j][0] = *(const bf16x8*)(bb + xsl0);                                 \
        bv[j][1] = *(const bf16x8*)(bb + xsl1);                                 \
      }                                                                         \
    }                                                                           \
    STG;                                                                        \
    G256_BAR();                                                                 \
    G256_LGKM();                                                                \
    __builtin_amdgcn_s_setprio(1);                                              \
    _Pragma("unroll")                                                           \
    for (int j=0;j<4;j++){                                                      \
      acc[(Q)*2+0][j] = __builtin_amdgcn_mfma_f32_16x16x32_bf16(a0, bv[j][0], acc[(Q)*2+0][j], 0,0,0); \
      acc[(Q)*2+0][j] = __builtin_amdgcn_mfma_f32_16x16x32_bf16(a1, bv[j][1], acc[(Q)*2+0][j], 0,0,0); \
      acc[(Q)*2+1][j] = __builtin_amdgcn_mfma_f32_16x16x32_bf16(a2, bv[j][0], acc[(Q)*2+1][j], 0,0,0); \
      acc[(Q)*2+1][j] = __builtin_amdgcn_mfma_f32_16x16x32_bf16(a3, bv[j][1], acc[(Q)*2+1][j], 0,0,0); \
    }                                                                           \
    __builtin_amdgcn_s_setprio(0);                                              \
    TAILV;                                                                      \
    G256_BAR();                                                                 \
  }while(0)

  for (int it2 = 0; it2 < NI; ++it2){
    const int t0 = it2*2;
    const bool s2 = (t0+2) < NT, s3 = (t0+3) < NT;
    const int k1 = (t0+1)<<6, k2 = (t0+2)<<6, k3 = (t0+3)<<6;

    // tile t0 (slot0)
    G256_PH(s0A, 0, 1, s0B, { STAGE(Agl,0,k1,s1A); STAGE(Agl,1,k1,s1A); }, );
    G256_PH(s0A, 1, 0, s0B, if (s2) STAGE(Bgl,0,k2,s0B), );
    G256_PH(s0A, 2, 0, s0B, if (s2) STAGE(Bgl,1,k2,s0B), );
    G256_PH(s0A, 3, 0, s0B, , if (s2) G256_VM4(); else G256_VM0(); );
    // tile t0+1 (slot1)
    G256_PH(s1A, 0, 1, s1B, if (s2) STAGE(Agl,0,k2,s0A), );
    G256_PH(s1A, 1, 0, s1B, if (s2) STAGE(Agl,1,k2,s0A), );
    G256_PH(s1A, 2, 0, s1B, if (s3) STAGE(Bgl,0,k3,s1B), );
    G256_PH(s1A, 3, 0, s1B, if (s3) STAGE(Bgl,1,k3,s1B),
            if (s3) G256_VM4(); else G256_VM0(); );
  }
#undef G256_PH

  // ---- epilogue ----
  const int mB = bm*256 + wm*128 + lk*4;
  const int nB = bn*256 + wn*64 + lr;
  if (CEPI==0 && gm==-1 && bn >= 36){
    // lin1 mlp tiles: block-uniform; bm in {0..5,8}; write gelu -> out2 (ld 15360)
    const int mq = (bm <= 5) ? mB : (mB - 512);
    #pragma unroll
    for (int fi=0; fi<8; fi++){
      #pragma unroll
      for (int j=0; j<4; j++){
        const int n = nB + j*16;
        const float bb = bias[n];
        #pragma unroll
        for (int r=0;r<4;r++){
          ((u16*)Cv2)[(size_t)(mq + fi*16 + r)*15360 + (n - 6144)] = f2b(gelu_f(acc[fi][j][r] + bb));
        }
      }
    }
  } else {
    #pragma unroll
    for (int fi=0; fi<8; fi++){
      #pragma unroll
      for (int j=0; j<4; j++){
        const int n = nB + j*16;
        const float bb = (CEPI==0) ? bias[n] : 0.f;
        #pragma unroll
        for (int r=0;r<4;r++){
          const int m = mB + fi*16 + r;
          if (CEPI==0){
            ((u16*)Cv)[(size_t)m*ldC + n] = f2b(acc[fi][j][r] + bb);
          } else {
            ((float*)Cv)[(size_t)sk*sC + (size_t)m*ldC + n] = acc[fi][j][r];
          }
        }
      }
    }
  }
}

// ================= flash attention (80 KB LDS + VGPR<=128 -> 2 blocks/CU) =================
__global__ __launch_bounds__(512,4)
void flash_attn(const u16* __restrict__ Qb, const u16* __restrict__ Kb,
                const u16* __restrict__ VT, const int* __restrict__ tmask,
                u16* __restrict__ out2)
{
  __shared__ __attribute__((aligned(16))) char smf[81920];
  char* Ks0 = smf;            // 2 x [64][128] = 32 KB
  char* Vs0 = smf + 32768;    // 2 x [128 d][64 k] = 32 KB (Q temp at start)
  char* Ps  = smf + 65536;    // [128 q][64 k] = 16 KB
  const int t = threadIdx.x, wid = t>>6, lane = t&63;
  const int lr = lane&15, hi = lane>>4;
  const int head = blockIdx.y, qt = blockIdx.x;
  const int q0 = qt*128;
  const u16* Qg = Qb + ((size_t)head*1792 + q0)*128;
  const u16* Kg = Kb + (size_t)head*2304*128;
  const u16* Vg = VT + (size_t)head*128*2304;
  const float SCALE = 0.08838834764831845f;

  u32 kbits = 0;
  #pragma unroll
  for (int i=0;i<16;i++) kbits |= (u32)(tmask[i*16 + lr] != 0) << i;
  int fqr[4];
  #pragma unroll
  for (int r=0;r<4;r++){
    const int q = q0 + wid*16 + hi*4 + r;
    fqr[r] = (q < 1536) ? 1 : (tmask[q-1536] != 0);
  }

  // ---- stage Q (temp in Vs0) + K tile 0 ----
  #pragma unroll
  for (int c=0;c<4;c++){
    const int s = c*512 + wid*64 + lane;
    const int row = s>>4, dsl = s&15;
    gload_lds16(Qg + (size_t)row*128 + ((dsl ^ (row&7))<<3),
                Vs0 + (size_t)(c*512 + wid*64)*16);
  }
  #pragma unroll
  for (int c=0;c<2;c++){
    const int s = c*512 + wid*64 + lane;
    const int row = s>>4, dsl = s&15;
    gload_lds16(Kg + (size_t)row*128 + ((dsl ^ (row&7))<<3),
                Ks0 + (size_t)(c*512 + wid*64)*16);
  }
  asm volatile("s_waitcnt vmcnt(0)" ::: "memory");
  __syncthreads();

  // hoist Q A-frags from Vs0 (temp)
  bf16x8 av[4];
  {
    const int row = wid*16 + lr;
    #pragma unroll
    for (int ks=0;ks<4;ks++)
      av[ks] = *(const bf16x8*)(Vs0 + row*256 + (((ks*4+hi) ^ (row&7))<<4));
  }
  asm volatile("s_waitcnt lgkmcnt(0)" ::: "memory");
  __builtin_amdgcn_sched_barrier(0);
  __syncthreads();

  // ---- stage V tile 0 (overwrites Q temp) ----
  #pragma unroll
  for (int c=0;c<2;c++){
    const int s = c*512 + wid*64 + lane;
    const int row = s>>3, dsl = s&7;
    gload_lds16(Vg + (size_t)row*2304 + ((dsl ^ (row&7))<<3),
                Vs0 + (size_t)(c*512 + wid*64)*16);
  }
  asm volatile("s_waitcnt vmcnt(0)" ::: "memory");
  __syncthreads();

  f32x4 acc[8] = {};
  float m_[4], l_[4];
  #pragma unroll
  for (int r=0;r<4;r++){ m_[r] = -3e38f; l_[r] = 0.f; }

  for (int kt = 0; kt < 36; ++kt){
    char* Kc = Ks0 + (kt&1)*16384;
    char* Vc = Vs0 + (kt&1)*16384;
    if (kt+1 < 36){
      char* Kn = Ks0 + ((kt+1)&1)*16384;
      char* Vn = Vs0 + ((kt+1)&1)*16384;
      #pragma unroll
      for (int c=0;c<2;c++){
        const int s = c*512 + wid*64 + lane;
        { const int row = s>>4, dsl = s&15;
          gload_lds16(Kg + (size_t)((kt+1)*64 + row)*128 + ((dsl ^ (row&7))<<3),
                      Kn + (size_t)(c*512 + wid*64)*16); }
        { const int row = s>>3, dsl = s&7;
          gload_lds16(Vg + (size_t)row*2304 + (kt+1)*64 + ((dsl ^ (row&7))<<3),
                      Vn + (size_t)(c*512 + wid*64)*16); }
      }
    }
    f32x4 sacc[4] = {};
    #pragma unroll
    for (int ks=0;ks<4;ks++){
      #pragma unroll
      for (int j=0;j<4;j++){
        const int row = j*16 + lr;
        bf16x8 bk = *(const bf16x8*)(Kc + row*256 + (((ks*4+hi) ^ (row&7))<<4));
        sacc[j] = __builtin_amdgcn_mfma_f32_16x16x32_bf16(av[ks], bk, sacc[j], 0,0,0);
      }
    }
    int gkj[4];
    #pragma unroll
    for (int j=0;j<4;j++)
      gkj[j] = (kt < 32) ? 1 : (int)((kbits >> ((kt-32)*4 + j)) & 1u);
    float p[4][4]; bool alw[4][4];
    float mt[4] = {-3e38f,-3e38f,-3e38f,-3e38f};
    #pragma unroll
    for (int j=0;j<4;j++){
      #pragma unroll
      for (int r=0;r<4;r++){
        const float s = sacc[j][r]*SCALE;
        const bool a = (fqr[r] == gkj[j]);
        alw[j][r] = a; p[j][r] = s;
        if (a) mt[r] = fmaxf(mt[r], s);
      }
    }
    #pragma unroll
    for (int r=0;r<4;r++){
      #pragma unroll
      for (int o=1;o<16;o<<=1) mt[r] = fmaxf(mt[r], __shfl_xor(mt[r], o, 64));
      const float nm = fmaxf(m_[r], mt[r]);
      const float cr = __expf(m_[r] - nm);
      m_[r] = nm;
      l_[r] *= cr;
      #pragma unroll
      for (int jp=0;jp<8;jp++) acc[jp][r] *= cr;
    }
    float rs[4] = {0.f,0.f,0.f,0.f};
    #pragma unroll
    for (int j=0;j<4;j++){
      #pragma unroll
      for (int r=0;r<4;r++){
        const float pv = alw[j][r] ? __expf(p[j][r] - m_[r]) : 0.f;
        p[j][r] = pv; rs[r] += pv;
      }
    }
    #pragma unroll
    for (int r=0;r<4;r++){
      #pragma unroll
      for (int o=1;o<16;o<<=1) rs[r] += __shfl_xor(rs[r], o, 64);
      l_[r] += rs[r];
    }
    #pragma unroll
    for (int j=0;j<4;j++){
      #pragma unroll
      for (int r=0;r<4;r++){
        const int q = wid*16 + hi*4 + r;
        const int k = j*16 + lr;
        *(u16*)(Ps + q*128 + (((k>>3) ^ (q&7))<<4) + (k&7)*2) = f2b(p[j][r]);
      }
    }
    asm volatile("s_waitcnt lgkmcnt(0)" ::: "memory");
    __builtin_amdgcn_sched_barrier(0);
    bf16x8 pa[2];
    {
      const int row = wid*16 + lr;
      #pragma unroll
      for (int ks2=0;ks2<2;ks2++)
        pa[ks2] = *(const bf16x8*)(Ps + row*128 + (((ks2*4+hi) ^ (row&7))<<4));
    }
    #pragma unroll
    for (int ks2=0;ks2<2;ks2++){
      #pragma unroll
      for (int jp=0;jp<8;jp++){
        const int row = jp*16 + lr;
        bf16x8 bvv = *(const bf16x8*)(Vc + row*128 + (((ks2*4+hi) ^ (row&7))<<4));
        acc[jp] = __builtin_amdgcn_mfma_f32_16x16x32_bf16(pa[ks2], bvv, acc[jp], 0,0,0);
      }
    }
    asm volatile("s_waitcnt vmcnt(0)" ::: "memory");
    __syncthreads();
  }

  float inv[4];
  #pragma unroll
  for (int r=0;r<4;r++) inv[r] = 1.f/l_[r];
  #pragma unroll
  for (int jp=0;jp<8;jp++){
    #pragma unroll
    for (int r=0;r<4;r++){
      const size_t q = q0 + wid*16 + hi*4 + r;
      out2[q*15360 + head*128 + jp*16 + lr] = f2b(acc[jp][r]*inv[r]);
    }
  }
}

// ---------------- lin2 finish: out = x + (p0+p1+p2+bias)*gate ----------------
__global__ void lin2_fin(const float* __restrict__ P, const float* __restrict__ x,
                         const float* __restrict__ bias, const float* __restrict__ gate,
                         float* __restrict__ out){
  const size_t e = ((size_t)blockIdx.x*256 + threadIdx.x)*4;   // over 1792*3072
  const int n = (int)(e % 3072);
  const size_t S = (size_t)1792*3072;
  float4 a = *(const float4*)(P + e);
  #pragma unroll
  for (int c=1;c<3;c++){
    const float4 p = *(const float4*)(P + c*S + e);
    a.x+=p.x; a.y+=p.y; a.z+=p.z; a.w+=p.w;
  }
  const float4 bb = *(const float4*)(bias + n);
  const float4 gg = *(const float4*)(gate + n);
  const float4 xv = *(const float4*)(x + e);
  float4 o;
  o.x = xv.x + (a.x+bb.x)*gg.x;
  o.y = xv.y + (a.y+bb.y)*gg.y;
  o.z = xv.z + (a.z+bb.z)*gg.z;
  o.w = xv.w + (a.w+bb.w)*gg.w;
  *(float4*)(out + e) = o;
}

// ---------------- host orchestration ----------------
extern "C" void kernel_launch(void* const* d_in, const int* in_sizes, int n_in,
                              void* d_out, int out_size, void* d_ws, size_t ws_size,
                              hipStream_t stream)
{
  (void)in_sizes; (void)n_in; (void)out_size; (void)ws_size;
  const float* x     = (const float*)d_in[0];
  const float* vec   = (const float*)d_in[1];
  const float* ref   = (const float*)d_in[2];
  const float* cosb  = (const float*)d_in[3];
  const float* sinb  = (const float*)d_in[4];
  const float* mod_w = (const float*)d_in[5];
  const float* mod_b = (const float*)d_in[6];
  const float* rf1_w = (const float*)d_in[7];
  const float* rf1_b = (const float*)d_in[8];
  const float* rf2_w = (const float*)d_in[9];
  const float* rf2_b = (const float*)d_in[10];
  const float* rln_g = (const float*)d_in[11];
  const float* rln_b = (const float*)d_in[12];
  const float* lin1_w= (const float*)d_in[13];
  const float* lin1_b= (const float*)d_in[14];
  const float* q_g   = (const float*)d_in[15];
  const float* k_g   = (const float*)d_in[16];
  const float* lin2_w= (const float*)d_in[17];
  const float* lin2_b= (const float*)d_in[18];
  const int*   tmask = (const int*)d_in[19];
  float* out = (float*)d_out;
  char* ws = (char*)d_ws;

  float* modp = (float*)(ws + 0);                    // 9216 f32
  float* part = (float*)(ws + 36864);                // 24*9216 f32
  u16*  w2t   = (u16*)(ws + 921600);                 // 3072 x 15360
  u16*  Qb    = (u16*)(ws + 95293440ll);             // 24 x 1792 x 128
  u16*  Kb    = (u16*)(ws + 106303488ll);            // 24 x 2304 x 128
  u16*  VT    = (u16*)(ws + 120459264ll);            // 24 x 128 x 2304
  u16*  out2  = (u16*)(ws + 134615040ll);            // 1792 x 15360
  u16*  w1t   = (u16*)(ws + 189665280ll);            // 21504 x 3072
  u16*  xc    = (u16*)(ws + 321785856ll);            // 2304 x 3072
  u16*  rf1t  = (u16*)(ws + 335941632ll);            // 3072 x 3072
  u16*  rf2t  = (u16*)(ws + 354816000ll);            // 3072 x 3072
  u16*  refb  = (u16*)(ws + 373690368ll);            // 512 x 3072
  u16*  tb    = (u16*)(ws + 376836096ll);            // 512 x 3072
  float* rtmp = (float*)(ws + 379981824ll);          // 512 x 3072 f32
  float* rp   = (float*)(ws + 386273280ll);          // 6 x 512 x 3072 f32 (pre-lin1 scratch)
  u16*  hbuf  = (u16*)(ws + 335941632ll);            // 2304 x 21504 (qkv cols only)
  float* p2b  = (float*)(ws + 189665280ll);          // 3 x 1792 x 3072 f32 (alias w1t/xc region)

  // 1) modulation GEMV
  modv_part<<<dim3(36,24),256,0,stream>>>(vec, mod_w, part);
  modv_reduce<<<36,256,0,stream>>>(part, mod_b, modp);
  // 2) weight conversions (64x64 tile, float4/u16x4)
  convT<<<dim3(48,48),  256,0,stream>>>(rf1_w, rf1t, 3072, 3072);
  convT<<<dim3(48,48),  256,0,stream>>>(rf2_w, rf2t, 3072, 3072);
  convT<<<dim3(336,48), 256,0,stream>>>(lin1_w, w1t, 3072, 21504);
  convT<<<dim3(48,240), 256,0,stream>>>(lin2_w, w2t, 15360, 3072);
  convertF2B<<<1536,256,0,stream>>>(ref, refb);
  // 3) LN + modulate
  ln_modulate<<<1792,256,0,stream>>>(x, modp, xc);
  // 4) ref MLP (split-K=6) -> LN
  gemm_bt<6><<<dim3(24,4,6),256,0,stream>>>(refb, rf1t, nullptr, rp, 512, 3072,3072,3072,
                                            512,512, (long long)512*3072);
  comb_gelu<<<1536,256,0,stream>>>(rp, rf1_b, tb);
  gemm_bt<6><<<dim3(24,4,6),256,0,stream>>>(tb, rf2t, nullptr, rp, 512, 3072,3072,3072,
                                            512,512, (long long)512*3072);
  comb_bias<<<1536,256,0,stream>>>(rp, rf2_b, rtmp);
  ln_ref<<<512,256,0,stream>>>(rtmp, rln_g, rln_b, xc);
  // 5) lin1 sparse map, 8-phase: 636 blocks; qkv cols -> hbuf, mlp cols gelu -> out2
  gemm256<0><<<636,512,0,stream>>>(xc, w1t, lin1_b, hbuf, out2, 3072, 3072, 21504, 84, 636, 0, 636, -1);
  // 6) q/k norm + rope, V transpose
  qk_prep<<<dim3(2304,24),128,0,stream>>>(hbuf, q_g, k_g, cosb, sinb, Qb, Kb);
  v_transpose<<<dim3(72,4,24),dim3(32,8),0,stream>>>(hbuf, VT);
  // 7) flash attention -> out2[:, :3072]
  flash_attn<<<dim3(14,24),512,0,stream>>>(Qb, Kb, VT, tmask, out2);
  // 8) lin2 split-K=3, 8-phase: M=1792 (7 tiles), N=3072 (12 tiles), Kc=5120 (NT=80), 252 blocks
  gemm256<1><<<252,512,0,stream>>>(out2, w2t, nullptr, p2b, nullptr, 5120, 15360, 3072, 12, 84,
                                   (long long)1792*3072, 252, 0);
  lin2_fin<<<5376,256,0,stream>>>(p2b, x, lin2_b, modp + 6144, out);
}

// Round 17
// 853.073 us; speedup vs baseline: 5.0101x; 1.0152x over previous
//
#include <hip/hip_runtime.h>
#include <cstdint>
#include <cstddef>

typedef unsigned short u16;
typedef unsigned int   u32;
typedef __bf16 bf16_t;
typedef bf16_t bf16x8 __attribute__((ext_vector_type(8)));
typedef float  f32x4  __attribute__((ext_vector_type(4)));
typedef u16    u16x4  __attribute__((ext_vector_type(4)));

// ---- problem constants ----
// H=3072 NH=24 HD=128 MLP_D=12288 IMG=1536 REF=512 TXT=256
// LQ = 1792, L2 = 2304, N1 = 21504, K2 = 15360

__device__ __forceinline__ float b2f(u16 b){ u32 u=((u32)b)<<16; float f; __builtin_memcpy(&f,&u,4); return f; }
__device__ __forceinline__ u16 f2b(float f){ u32 u; __builtin_memcpy(&u,&f,4); u = u + 0x7fffu + ((u>>16)&1u); return (u16)(u>>16); }
// gelu(x) = x * sigmoid(1.5957691*(x+0.044715x^3))
__device__ __forceinline__ float gelu_f(float x){
  const float u2 = 1.5957691216057308f*(x + 0.044715f*x*x*x);
  return x/(1.f + __expf(-u2));
}

__device__ __forceinline__ void gload_lds16(const void* g, void* l){
  __builtin_amdgcn_global_load_lds((const __attribute__((address_space(1))) void*)g,
                                   (__attribute__((address_space(3))) void*)l, 16, 0, 0);
}

template<int NW, bool MX>
__device__ __forceinline__ float bred(float v, float* red){
  #pragma unroll
  for (int o=32;o;o>>=1){ float u=__shfl_down(v,o,64); v = MX? fmaxf(v,u) : v+u; }
  const int t = threadIdx.x;
  if ((t&63)==0) red[t>>6]=v;
  __syncthreads();
  float r = red[0];
  #pragma unroll
  for (int i=1;i<NW;i++) r = MX? fmaxf(r,red[i]) : r+red[i];
  __syncthreads();
  return r;
}

// ---------------- mod GEMV ----------------
__global__ void modv_part(const float* __restrict__ vec, const float* __restrict__ W,
                          float* __restrict__ part){
  __shared__ float s[128];
  const int t = threadIdx.x;
  const int j = blockIdx.x*256 + t;
  const int i0 = blockIdx.y*128;
  if (t < 128){ float v = vec[i0+t]; s[t] = v/(1.f+__expf(-v)); }
  __syncthreads();
  float acc = 0.f;
  #pragma unroll 8
  for (int i=0;i<128;i++) acc += s[i]*W[(size_t)(i0+i)*9216 + j];
  part[(size_t)blockIdx.y*9216 + j] = acc;
}
__global__ void modv_reduce(const float* __restrict__ part, const float* __restrict__ mb,
                            float* __restrict__ modp){
  const int j = blockIdx.x*256 + threadIdx.x;
  float a = mb[j];
  #pragma unroll
  for (int c=0;c<24;c++) a += part[(size_t)c*9216 + j];
  modp[j] = a;
}

// ---------------- fp32 (K x N) -> bf16 transposed (N x K), 64x64 tile ----------------
__global__ __launch_bounds__(256)
void convT(const float* __restrict__ W, u16* __restrict__ Wt, int Kd, int Nd){
  __shared__ float Ls[64][65];
  const int t = threadIdx.x;
  const int n0 = blockIdx.x*64, k0 = blockIdx.y*64;
  const int tr = t>>4;        // 0..15
  const int tc = (t&15)*4;    // 0,4,...,60
  #pragma unroll
  for (int p=0;p<4;p++){
    const int kk = tr + p*16;
    const float4 v = *(const float4*)(W + (size_t)(k0+kk)*Nd + n0 + tc);
    Ls[kk][tc+0]=v.x; Ls[kk][tc+1]=v.y; Ls[kk][tc+2]=v.z; Ls[kk][tc+3]=v.w;
  }
  __syncthreads();
  #pragma unroll
  for (int p=0;p<4;p++){
    const int nn = tr + p*16;
    u16x4 o;
    o.x = f2b(Ls[tc+0][nn]); o.y = f2b(Ls[tc+1][nn]);
    o.z = f2b(Ls[tc+2][nn]); o.w = f2b(Ls[tc+3][nn]);
    *(u16x4*)(Wt + (size_t)(n0+nn)*Kd + k0 + tc) = o;
  }
}

__global__ void convertF2B(const float* __restrict__ src, u16* __restrict__ dst){
  const size_t i = ((size_t)blockIdx.x*256 + threadIdx.x)*4;
  const float4 v = *(const float4*)(src+i);
  u16x4 o; o.x=f2b(v.x); o.y=f2b(v.y); o.z=f2b(v.z); o.w=f2b(v.w);
  *(u16x4*)(dst+i) = o;
}

// ---------------- LN(x)*(1+scale)+shift -> xc (bf16) ----------------
__global__ void ln_modulate(const float* __restrict__ x, const float* __restrict__ modp,
                            u16* __restrict__ xc){
  __shared__ float red[4];
  const int row = blockIdx.x, t = threadIdx.x;
  const float* xr = x + (size_t)row*3072;
  float4 v[3]; float s=0.f, ss=0.f;
  #pragma unroll
  for (int k=0;k<3;k++){
    v[k] = *(const float4*)(xr + t*4 + k*1024);
    s  += v[k].x+v[k].y+v[k].z+v[k].w;
    ss += v[k].x*v[k].x+v[k].y*v[k].y+v[k].z*v[k].z+v[k].w*v[k].w;
  }
  s  = bred<4,false>(s, red);
  ss = bred<4,false>(ss, red);
  const float mean = s*(1.f/3072.f);
  const float inv = rsqrtf(ss*(1.f/3072.f)-mean*mean + 1e-6f);
  const int orow = row<1536 ? row : row+512;
  u16* o = xc + (size_t)orow*3072;
  const float* shiftp = modp; const float* scalep = modp+3072;
  #pragma unroll
  for (int k=0;k<3;k++){
    const int j = t*4 + k*1024;
    const float4 sc = *(const float4*)(scalep+j);
    const float4 sh = *(const float4*)(shiftp+j);
    u16x4 ov;
    ov.x = f2b((v[k].x-mean)*inv*(1.f+sc.x)+sh.x);
    ov.y = f2b((v[k].y-mean)*inv*(1.f+sc.y)+sh.y);
    ov.z = f2b((v[k].z-mean)*inv*(1.f+sc.z)+sh.z);
    ov.w = f2b((v[k].w-mean)*inv*(1.f+sc.w)+sh.w);
    *(u16x4*)(o+j) = ov;
  }
}

// ---------------- fused: sum 6 split-K partials + rf2_b, then LN(.)*g+b -> xc rows [1536,2048) ----------------
__global__ void comb_ln_ref(const float* __restrict__ P, const float* __restrict__ rb,
                            const float* __restrict__ g, const float* __restrict__ be,
                            u16* __restrict__ xc){
  __shared__ float red[4];
  const int row = blockIdx.x, t = threadIdx.x;
  const size_t S = (size_t)512*3072;
  float4 v[3]; float s=0.f, ss=0.f;
  #pragma unroll
  for (int k=0;k<3;k++){
    const int j = t*4 + k*1024;
    const size_t e = (size_t)row*3072 + j;
    float4 a = *(const float4*)(P + e);
    #pragma unroll
    for (int c=1;c<6;c++){
      const float4 p = *(const float4*)(P + c*S + e);
      a.x+=p.x; a.y+=p.y; a.z+=p.z; a.w+=p.w;
    }
    const float4 bb = *(const float4*)(rb + j);
    a.x+=bb.x; a.y+=bb.y; a.z+=bb.z; a.w+=bb.w;
    v[k] = a;
    s  += a.x+a.y+a.z+a.w;
    ss += a.x*a.x+a.y*a.y+a.z*a.z+a.w*a.w;
  }
  s  = bred<4,false>(s, red);
  ss = bred<4,false>(ss, red);
  const float mean = s*(1.f/3072.f);
  const float inv = rsqrtf(ss*(1.f/3072.f)-mean*mean + 1e-6f);
  u16* o = xc + (size_t)(1536+row)*3072;
  #pragma unroll
  for (int k=0;k<3;k++){
    const int j = t*4 + k*1024;
    const float4 gv = *(const float4*)(g+j);
    const float4 bv = *(const float4*)(be+j);
    u16x4 ov;
    ov.x = f2b((v[k].x-mean)*inv*gv.x+bv.x);
    ov.y = f2b((v[k].y-mean)*inv*gv.y+bv.y);
    ov.z = f2b((v[k].z-mean)*inv*gv.z+bv.z);
    ov.w = f2b((v[k].w-mean)*inv*gv.w+bv.w);
    *(u16x4*)(o+j) = ov;
  }
}

// ---------------- RMS-norm + RoPE on q,k from h (64 threads, wave-shuffle, paired) ----------------
__global__ void qk_prep(const u16* __restrict__ h, const float* __restrict__ qg,
                        const float* __restrict__ kg, const float* __restrict__ cosb,
                        const float* __restrict__ sinb, u16* __restrict__ Q,
                        u16* __restrict__ Kb){
  const int row = blockIdx.x, hd = blockIdx.y, p = threadIdx.x; // 64 threads, pair p
  const u16* hr = h + (size_t)row*21504;
  const int d0 = p*2;
  const u32 kp = *(const u32*)(hr + 3072 + hd*128 + d0);
  const bool doq = (row < 1536) || (row >= 2048);
  const u32 qp = doq ? *(const u32*)(hr + hd*128 + d0) : 0u;
  const float k0 = b2f((u16)(kp&0xffffu)), k1 = b2f((u16)(kp>>16));
  const float q0 = b2f((u16)(qp&0xffffu)), q1 = b2f((u16)(qp>>16));
  float a = k0*k0 + k1*k1;
  float b = q0*q0 + q1*q1;
  #pragma unroll
  for (int o=32;o;o>>=1){ a += __shfl_xor(a,o,64); b += __shfl_xor(b,o,64); }
  const float kinv = rsqrtf(a*(1.f/128.f) + 1e-6f);
  const float qinv = rsqrtf(b*(1.f/128.f) + 1e-6f);
  float kn0 = k0*kinv*kg[d0], kn1 = k1*kinv*kg[d0+1];
  float qn0 = q0*qinv*qg[d0], qn1 = q1*qinv*qg[d0+1];
  if (row < 1536){
    const float c0 = cosb[row*128+d0], c1 = cosb[row*128+d0+1];
    const float s0 = sinb[row*128+d0], s1 = sinb[row*128+d0+1];
    const float tk0 = kn0*c0 - kn1*s0;
    const float tk1 = kn1*c1 + kn0*s1;
    kn0 = tk0; kn1 = tk1;
    const float tq0 = qn0*c0 - qn1*s0;
    const float tq1 = qn1*c1 + qn0*s1;
    qn0 = tq0; qn1 = tq1;
  }
  *(u32*)(Kb + ((size_t)hd*2304 + row)*128 + d0) = (u32)f2b(kn0) | ((u32)f2b(kn1)<<16);
  if (doq){
    const int qrow = row<1536 ? row : row-512;
    *(u32*)(Q + ((size_t)hd*1792 + qrow)*128 + d0) = (u32)f2b(qn0) | ((u32)f2b(qn1)<<16);
  }
}

// ---------------- V transpose: 64x64 tile, ushort4 ----------------
__global__ __launch_bounds__(256)
void v_transpose(const u16* __restrict__ h, u16* __restrict__ VT){
  __shared__ u16 Ls[64][68];
  const int t = threadIdx.x;
  const int l0 = blockIdx.x*64, d0 = blockIdx.y*64, hd = blockIdx.z;
  const int tr = t>>4, tc = (t&15)*4;
  #pragma unroll
  for (int p=0;p<4;p++){
    const int kk = tr + p*16;
    const ushort4 v = *(const ushort4*)(h + (size_t)(l0+kk)*21504 + 6144 + hd*128 + d0 + tc);
    Ls[kk][tc] = v.x; Ls[kk][tc+1] = v.y; Ls[kk][tc+2] = v.z; Ls[kk][tc+3] = v.w;
  }
  __syncthreads();
  #pragma unroll
  for (int p=0;p<4;p++){
    const int nn = tr + p*16;
    ushort4 o;
    o.x = Ls[tc][nn]; o.y = Ls[tc+1][nn]; o.z = Ls[tc+2][nn]; o.w = Ls[tc+3][nn];
    *(ushort4*)(VT + ((size_t)hd*128 + d0+nn)*2304 + l0 + tc) = o;
  }
}

// ---------------- 128x128 2-barrier GEMM (small shapes; EPI 6 = f32 split-K partial) ----------------
template<int EPI>
__global__ __launch_bounds__(256)
void gemm_bt(const u16* __restrict__ A, const u16* __restrict__ Bt,
             const float* __restrict__ bias, void* __restrict__ Cv,
             int K, int ldA, int ldB, int ldC,
             long long sA, long long sB, long long sC)
{
  __shared__ u16 As[128*32];
  __shared__ u16 Bs[128*32];
  const int t = threadIdx.x;
  const int w = t>>6, lane = t&63;
  const int bm = blockIdx.y, bn = blockIdx.x, bz = blockIdx.z;
  const u16* Ab = A + (size_t)((long long)bz*sA) + (size_t)bm*128*ldA;
  const u16* Bb = Bt + (size_t)((long long)bz*sB) + (size_t)bn*128*ldB;
  const int wm = w>>1, wn = w&1;
  const int lr = lane&15, lk = lane>>4;
  const int row0 = t>>2, kp0 = (t&3)*8;
  char* AsB = (char*)As; char* BsB = (char*)Bs;
  const int off0 = w*1024;
  const int off1 = 4096 + w*1024;
  f32x4 acc[4][4] = {};

  for (int kt = 0; kt < K; kt += 32){
    __syncthreads();
    gload_lds16(Ab + (size_t)row0*ldA + kt + kp0,      AsB + off0);
    gload_lds16(Ab + (size_t)(row0+64)*ldA + kt + kp0, AsB + off1);
    gload_lds16(Bb + (size_t)row0*ldB + kt + kp0,      BsB + off0);
    gload_lds16(Bb + (size_t)(row0+64)*ldB + kt + kp0, BsB + off1);
    __syncthreads();
    bf16x8 av[4], bv[4];
    #pragma unroll
    for (int i=0;i<4;i++) av[i] = *(const bf16x8*)(As + (wm*64+i*16+lr)*32 + lk*8);
    #pragma unroll
    for (int j=0;j<4;j++) bv[j] = *(const bf16x8*)(Bs + (wn*64+j*16+lr)*32 + lk*8);
    #pragma unroll
    for (int i=0;i<4;i++)
      #pragma unroll
      for (int j=0;j<4;j++)
        acc[i][j] = __builtin_amdgcn_mfma_f32_16x16x32_bf16(av[i], bv[j], acc[i][j], 0,0,0);
  }

  const int mBase = bm*128 + wm*64;
  const int nBase = bn*128 + wn*64;
  #pragma unroll
  for (int i=0;i<4;i++){
    #pragma unroll
    for (int j=0;j<4;j++){
      #pragma unroll
      for (int r=0;r<4;r++){
        const int m = mBase + i*16 + lk*4 + r;
        const int n = nBase + j*16 + lr;
        const float v = acc[i][j][r];
        const long long idx = (long long)bz*sC + (long long)m*ldC + n;
        if (EPI==6){
          ((float*)Cv)[idx] = v;
        } else {
          ((u16*)Cv)[idx] = f2b(v + bias[n]);
        }
      }
    }
  }
}

// ---------------- split-K combine for ref MLP layer 1 (gelu) ----------------
__global__ void comb_gelu(const float* __restrict__ P, const float* __restrict__ b,
                          u16* __restrict__ o){
  const size_t e = ((size_t)blockIdx.x*256 + threadIdx.x)*4;   // over 512*3072
  const int n = (int)(e % 3072);
  const size_t S = (size_t)512*3072;
  float4 a = *(const float4*)(P + e);
  #pragma unroll
  for (int c=1;c<6;c++){
    const float4 p = *(const float4*)(P + c*S + e);
    a.x+=p.x; a.y+=p.y; a.z+=p.z; a.w+=p.w;
  }
  const float4 bb = *(const float4*)(b + n);
  u16x4 ov;
  ov.x = f2b(gelu_f(a.x+bb.x)); ov.y = f2b(gelu_f(a.y+bb.y));
  ov.z = f2b(gelu_f(a.z+bb.z)); ov.w = f2b(gelu_f(a.w+bb.w));
  *(u16x4*)(o + e) = ov;
}

// ================= 256x256 GEMM, m201 8-phase schedule (T1+T2+T3+T4+T5) =================
// 2 K-tiles per iteration, 8 phases; counted vmcnt(4) only at phases 4 and 8.
// Staging ledger (tile tau -> slot tau&1):
//  P1: A(t+1)->s1A   P2: B0(t+2)->s0B  P3: B1(t+2)->s0B
//  P5: A0(t+2)->s0A  P6: A1(t+2)->s0A  P7: B0(t+3)->s1B  P8: B1(t+3)->s1B
// Region free-times: s0B after P1, s0A after P4, s1B after P5, s1A after P8. NT must be EVEN.
// CEPI 0: C(bf16)=acc+bias; lin1 mlp tiles (gm==-1 && bn>=36) -> Cv2=out2 with gelu.
// CEPI 1: C(f32 at sk*sC)=acc (split-K partial).
// gm>0: grouped bands; gm==0: split-K; gm==-1: lin1 sparse 636-tile map. All XCD-swizzled.
#define G256_BAR()  __builtin_amdgcn_s_barrier()
#define G256_LGKM() do{ asm volatile("s_waitcnt lgkmcnt(0)" ::: "memory"); \
                        __builtin_amdgcn_sched_barrier(0); }while(0)
#define G256_VM4()  asm volatile("s_waitcnt vmcnt(4)" ::: "memory")
#define G256_VM0()  asm volatile("s_waitcnt vmcnt(0)" ::: "memory")

__device__ __forceinline__ void lin1_map(int tw, int& bm, int& bn){
  if (tw < 504){
    const int band = tw/252; const int rr = tw - band*252;
    bn = rr/3; bm = band*3 + (rr - bn*3);
  } else if (tw < 588){
    bm = 8; bn = tw - 504;
  } else {
    const int rem = tw - 588;
    bm = 6 + (rem&1); bn = 12 + (rem>>1);
  }
}

template<int CEPI>
__global__ __launch_bounds__(512,2)
void gemm256(const u16* __restrict__ A, const u16* __restrict__ Bt,
             const float* __restrict__ bias, void* __restrict__ Cv, void* __restrict__ Cv2,
             int Kc, int ld, int ldC, int nbn, int ntile, long long sC, int nwg, int gm)
{
  __shared__ char smem[131072];
  const int t = threadIdx.x;
  const int wid = t>>6, lane = t&63;
  const int lr = lane&15, lk = lane>>4;
  const int wm = wid>>2, wn = wid&3;

  // bijective XCD swizzle (m204)
  const int orig = blockIdx.x;
  const int q8 = nwg>>3, r8 = nwg&7;
  const int xcd = orig&7, jj = orig>>3;
  const int wg = (xcd<r8 ? xcd*(q8+1) : r8*(q8+1) + (xcd-r8)*q8) + jj;
  int sk, bm, bn;
  if (gm == -1){
    sk = 0; lin1_map(wg, bm, bn);
  } else if (gm > 0){
    const int band = wg / (gm*nbn);
    const int rr = wg - band*(gm*nbn);
    bn = rr / gm;
    bm = band*gm + (rr - bn*gm);
    sk = 0;
  } else {
    sk = wg / ntile;
    const int rem = wg - sk*ntile;
    bm = rem / nbn; bn = rem % nbn;
  }

  const u16* Agl = A  + (size_t)bm*256*ld + (size_t)sk*Kc;
  const u16* Bgl = Bt + (size_t)bn*256*ld + (size_t)sk*Kc;
  const int NT = Kc>>6;     // even
  const int NI = NT>>1;

  // staging: dest idx d0 in [0,512): row sr=d0>>3, dest 16B-slot=d0&7;
  // global source slot = dest_slot ^ (sr&7) (inverse swizzle, rule 21).
  const int d0 = wid*64 + lane;
  const int sr = d0>>3;
  const size_t soff = (size_t)sr*ld + (size_t)(((d0&7)^(sr&7))<<3);
  // read-side swizzled 16B-slot byte offsets
  const int xsl0 = ((lk    ) ^ (lr&7))<<4;   // ks=0
  const int xsl1 = ((lk | 4) ^ (lr&7))<<4;   // ks=1

  char* s0A = smem;
  char* s0B = smem + 32768;
  char* s1A = smem + 65536;
  char* s1B = smem + 98304;

  f32x4 acc[8][4] = {};
  bf16x8 bv[4][2];

  auto STAGE = [&](const u16* g, int h, int kt, char* ldsMat){
    const u16* s0 = g + (size_t)(h*128)*ld + kt + soff;
    char* l0 = ldsMat + h*16384 + wid*1024;
    gload_lds16(s0, l0);
    gload_lds16(s0 + (size_t)64*ld, l0 + 8192);
  };

  // ---- prologue: A(0)->s0A, B(0)->s0B, B(1)->s1B; leave B(1) in flight ----
  STAGE(Agl, 0, 0, s0A);
  STAGE(Agl, 1, 0, s0A);
  STAGE(Bgl, 0, 0, s0B);
  STAGE(Bgl, 1, 0, s0B);
  STAGE(Bgl, 0, 64, s1B);
  STAGE(Bgl, 1, 64, s1B);
  G256_VM4();
  G256_BAR();

#define G256_PH(SA, Q, READB, SB, STG, TAILV)                                   \
  do{                                                                           \
    const char* ab = SA + (wm*128 + (Q)*32 + lr)*128;                           \
    bf16x8 a0 = *(const bf16x8*)(ab + xsl0);                                    \
    bf16x8 a1 = *(const bf16x8*)(ab + xsl1);                                    \
    bf16x8 a2 = *(const bf16x8*)(ab + 2048 + xsl0);                             \
    bf16x8 a3 = *(const bf16x8*)(ab + 2048 + xsl1);                             \
    if (READB){                                                                 \
      _Pragma("unroll")                                                         \
      for (int j=0;j<4;j++){                                                    \
        const char* bb = SB + (wn*64 + j*16 + lr)*128;                          \
        bv[j][0] = *(const bf16x8*)(bb + xsl0);                                 \
        bv[j][1] = *(const bf16x8*)(bb + xsl1);                                 \
      }                                                                         \
    }                                                                           \
    STG;                                                                        \
    G256_BAR();                                                                 \
    G256_LGKM();                                                                \
    __builtin_amdgcn_s_setprio(1);                                              \
    _Pragma("unroll")                                                           \
    for (int j=0;j<4;j++){                                                      \
      acc[(Q)*2+0][j] = __builtin_amdgcn_mfma_f32_16x16x32_bf16(a0, bv[j][0], acc[(Q)*2+0][j], 0,0,0); \
      acc[(Q)*2+0][j] = __builtin_amdgcn_mfma_f32_16x16x32_bf16(a1, bv[j][1], acc[(Q)*2+0][j], 0,0,0); \
      acc[(Q)*2+1][j] = __builtin_amdgcn_mfma_f32_16x16x32_bf16(a2, bv[j][0], acc[(Q)*2+1][j], 0,0,0); \
      acc[(Q)*2+1][j] = __builtin_amdgcn_mfma_f32_16x16x32_bf16(a3, bv[j][1], acc[(Q)*2+1][j], 0,0,0); \
    }                                                                           \
    __builtin_amdgcn_s_setprio(0);                                              \
    TAILV;                                                                      \
    G256_BAR();                                                                 \
  }while(0)

  for (int it2 = 0; it2 < NI; ++it2){
    const int t0 = it2*2;
    const bool s2 = (t0+2) < NT, s3 = (t0+3) < NT;
    const int k1 = (t0+1)<<6, k2 = (t0+2)<<6, k3 = (t0+3)<<6;

    // tile t0 (slot0)
    G256_PH(s0A, 0, 1, s0B, { STAGE(Agl,0,k1,s1A); STAGE(Agl,1,k1,s1A); }, );
    G256_PH(s0A, 1, 0, s0B, if (s2) STAGE(Bgl,0,k2,s0B), );
    G256_PH(s0A, 2, 0, s0B, if (s2) STAGE(Bgl,1,k2,s0B), );
    G256_PH(s0A, 3, 0, s0B, , if (s2) G256_VM4(); else G256_VM0(); );
    // tile t0+1 (slot1)
    G256_PH(s1A, 0, 1, s1B, if (s2) STAGE(Agl,0,k2,s0A), );
    G256_PH(s1A, 1, 0, s1B, if (s2) STAGE(Agl,1,k2,s0A), );
    G256_PH(s1A, 2, 0, s1B, if (s3) STAGE(Bgl,0,k3,s1B), );
    G256_PH(s1A, 3, 0, s1B, if (s3) STAGE(Bgl,1,k3,s1B),
            if (s3) G256_VM4(); else G256_VM0(); );
  }
#undef G256_PH

  // ---- epilogue ----
  const int mB = bm*256 + wm*128 + lk*4;
  const int nB = bn*256 + wn*64 + lr;
  if (CEPI==0 && gm==-1 && bn >= 36){
    // lin1 mlp tiles: block-uniform; bm in {0..5,8}; write gelu -> out2 (ld 15360)
    const int mq = (bm <= 5) ? mB : (mB - 512);
    #pragma unroll
    for (int fi=0; fi<8; fi++){
      #pragma unroll
      for (int j=0; j<4; j++){
        const int n = nB + j*16;
        const float bb = bias[n];
        #pragma unroll
        for (int r=0;r<4;r++){
          ((u16*)Cv2)[(size_t)(mq + fi*16 + r)*15360 + (n - 6144)] = f2b(gelu_f(acc[fi][j][r] + bb));
        }
      }
    }
  } else {
    #pragma unroll
    for (int fi=0; fi<8; fi++){
      #pragma unroll
      for (int j=0; j<4; j++){
        const int n = nB + j*16;
        const float bb = (CEPI==0) ? bias[n] : 0.f;
        #pragma unroll
        for (int r=0;r<4;r++){
          const int m = mB + fi*16 + r;
          if (CEPI==0){
            ((u16*)Cv)[(size_t)m*ldC + n] = f2b(acc[fi][j][r] + bb);
          } else {
            ((float*)Cv)[(size_t)sk*sC + (size_t)m*ldC + n] = acc[fi][j][r];
          }
        }
      }
    }
  }
}

// ================= flash attention (80 KB LDS + VGPR<=128 -> 2 blocks/CU) =================
__global__ __launch_bounds__(512,4)
void flash_attn(const u16* __restrict__ Qb, const u16* __restrict__ Kb,
                const u16* __restrict__ VT, const int* __restrict__ tmask,
                u16* __restrict__ out2)
{
  __shared__ __attribute__((aligned(16))) char smf[81920];
  char* Ks0 = smf;            // 2 x [64][128] = 32 KB
  char* Vs0 = smf + 32768;    // 2 x [128 d][64 k] = 32 KB (Q temp at start)
  char* Ps  = smf + 65536;    // [128 q][64 k] = 16 KB
  const int t = threadIdx.x, wid = t>>6, lane = t&63;
  const int lr = lane&15, hi = lane>>4;
  const int head = blockIdx.y, qt = blockIdx.x;
  const int q0 = qt*128;
  const u16* Qg = Qb + ((size_t)head*1792 + q0)*128;
  const u16* Kg = Kb + (size_t)head*2304*128;
  const u16* Vg = VT + (size_t)head*128*2304;
  const float SCALE = 0.08838834764831845f;

  u32 kbits = 0;
  #pragma unroll
  for (int i=0;i<16;i++) kbits |= (u32)(tmask[i*16 + lr] != 0) << i;
  int fqr[4];
  #pragma unroll
  for (int r=0;r<4;r++){
    const int q = q0 + wid*16 + hi*4 + r;
    fqr[r] = (q < 1536) ? 1 : (tmask[q-1536] != 0);
  }

  // ---- stage Q (temp in Vs0) + K tile 0 ----
  #pragma unroll
  for (int c=0;c<4;c++){
    const int s = c*512 + wid*64 + lane;
    const int row = s>>4, dsl = s&15;
    gload_lds16(Qg + (size_t)row*128 + ((dsl ^ (row&7))<<3),
                Vs0 + (size_t)(c*512 + wid*64)*16);
  }
  #pragma unroll
  for (int c=0;c<2;c++){
    const int s = c*512 + wid*64 + lane;
    const int row = s>>4, dsl = s&15;
    gload_lds16(Kg + (size_t)row*128 + ((dsl ^ (row&7))<<3),
                Ks0 + (size_t)(c*512 + wid*64)*16);
  }
  asm volatile("s_waitcnt vmcnt(0)" ::: "memory");
  __syncthreads();

  // hoist Q A-frags from Vs0 (temp)
  bf16x8 av[4];
  {
    const int row = wid*16 + lr;
    #pragma unroll
    for (int ks=0;ks<4;ks++)
      av[ks] = *(const bf16x8*)(Vs0 + row*256 + (((ks*4+hi) ^ (row&7))<<4));
  }
  asm volatile("s_waitcnt lgkmcnt(0)" ::: "memory");
  __builtin_amdgcn_sched_barrier(0);
  __syncthreads();

  // ---- stage V tile 0 (overwrites Q temp) ----
  #pragma unroll
  for (int c=0;c<2;c++){
    const int s = c*512 + wid*64 + lane;
    const int row = s>>3, dsl = s&7;
    gload_lds16(Vg + (size_t)row*2304 + ((dsl ^ (row&7))<<3),
                Vs0 + (size_t)(c*512 + wid*64)*16);
  }
  asm volatile("s_waitcnt vmcnt(0)" ::: "memory");
  __syncthreads();

  f32x4 acc[8] = {};
  float m_[4], l_[4];
  #pragma unroll
  for (int r=0;r<4;r++){ m_[r] = -3e38f; l_[r] = 0.f; }

  for (int kt = 0; kt < 36; ++kt){
    char* Kc = Ks0 + (kt&1)*16384;
    char* Vc = Vs0 + (kt&1)*16384;
    if (kt+1 < 36){
      char* Kn = Ks0 + ((kt+1)&1)*16384;
      char* Vn = Vs0 + ((kt+1)&1)*16384;
      #pragma unroll
      for (int c=0;c<2;c++){
        const int s = c*512 + wid*64 + lane;
        { const int row = s>>4, dsl = s&15;
          gload_lds16(Kg + (size_t)((kt+1)*64 + row)*128 + ((dsl ^ (row&7))<<3),
                      Kn + (size_t)(c*512 + wid*64)*16); }
        { const int row = s>>3, dsl = s&7;
          gload_lds16(Vg + (size_t)row*2304 + (kt+1)*64 + ((dsl ^ (row&7))<<3),
                      Vn + (size_t)(c*512 + wid*64)*16); }
      }
    }
    f32x4 sacc[4] = {};
    #pragma unroll
    for (int ks=0;ks<4;ks++){
      #pragma unroll
      for (int j=0;j<4;j++){
        const int row = j*16 + lr;
        bf16x8 bk = *(const bf16x8*)(Kc + row*256 + (((ks*4+hi) ^ (row&7))<<4));
        sacc[j] = __builtin_amdgcn_mfma_f32_16x16x32_bf16(av[ks], bk, sacc[j], 0,0,0);
      }
    }
    int gkj[4];
    #pragma unroll
    for (int j=0;j<4;j++)
      gkj[j] = (kt < 32) ? 1 : (int)((kbits >> ((kt-32)*4 + j)) & 1u);
    float p[4][4]; bool alw[4][4];
    float mt[4] = {-3e38f,-3e38f,-3e38f,-3e38f};
    #pragma unroll
    for (int j=0;j<4;j++){
      #pragma unroll
      for (int r=0;r<4;r++){
        const float s = sacc[j][r]*SCALE;
        const bool a = (fqr[r] == gkj[j]);
        alw[j][r] = a; p[j][r] = s;
        if (a) mt[r] = fmaxf(mt[r], s);
      }
    }
    #pragma unroll
    for (int r=0;r<4;r++){
      #pragma unroll
      for (int o=1;o<16;o<<=1) mt[r] = fmaxf(mt[r], __shfl_xor(mt[r], o, 64));
      const float nm = fmaxf(m_[r], mt[r]);
      const float cr = __expf(m_[r] - nm);
      m_[r] = nm;
      l_[r] *= cr;
      #pragma unroll
      for (int jp=0;jp<8;jp++) acc[jp][r] *= cr;
    }
    float rs[4] = {0.f,0.f,0.f,0.f};
    #pragma unroll
    for (int j=0;j<4;j++){
      #pragma unroll
      for (int r=0;r<4;r++){
        const float pv = alw[j][r] ? __expf(p[j][r] - m_[r]) : 0.f;
        p[j][r] = pv; rs[r] += pv;
      }
    }
    #pragma unroll
    for (int r=0;r<4;r++){
      #pragma unroll
      for (int o=1;o<16;o<<=1) rs[r] += __shfl_xor(rs[r], o, 64);
      l_[r] += rs[r];
    }
    #pragma unroll
    for (int j=0;j<4;j++){
      #pragma unroll
      for (int r=0;r<4;r++){
        const int q = wid*16 + hi*4 + r;
        const int k = j*16 + lr;
        *(u16*)(Ps + q*128 + (((k>>3) ^ (q&7))<<4) + (k&7)*2) = f2b(p[j][r]);
      }
    }
    asm volatile("s_waitcnt lgkmcnt(0)" ::: "memory");
    __builtin_amdgcn_sched_barrier(0);
    bf16x8 pa[2];
    {
      const int row = wid*16 + lr;
      #pragma unroll
      for (int ks2=0;ks2<2;ks2++)
        pa[ks2] = *(const bf16x8*)(Ps + row*128 + (((ks2*4+hi) ^ (row&7))<<4));
    }
    #pragma unroll
    for (int ks2=0;ks2<2;ks2++){
      #pragma unroll
      for (int jp=0;jp<8;jp++){
        const int row = jp*16 + lr;
        bf16x8 bvv = *(const bf16x8*)(Vc + row*128 + (((ks2*4+hi) ^ (row&7))<<4));
        acc[jp] = __builtin_amdgcn_mfma_f32_16x16x32_bf16(pa[ks2], bvv, acc[jp], 0,0,0);
      }
    }
    asm volatile("s_waitcnt vmcnt(0)" ::: "memory");
    __syncthreads();
  }

  float inv[4];
  #pragma unroll
  for (int r=0;r<4;r++) inv[r] = 1.f/l_[r];
  #pragma unroll
  for (int jp=0;jp<8;jp++){
    #pragma unroll
    for (int r=0;r<4;r++){
      const size_t q = q0 + wid*16 + hi*4 + r;
      out2[q*15360 + head*128 + jp*16 + lr] = f2b(acc[jp][r]*inv[r]);
    }
  }
}

// ---------------- lin2 finish: out = x + (p0+p1+p2+bias)*gate ----------------
__global__ void lin2_fin(const float* __restrict__ P, const float* __restrict__ x,
                         const float* __restrict__ bias, const float* __restrict__ gate,
                         float* __restrict__ out){
  const size_t e = ((size_t)blockIdx.x*256 + threadIdx.x)*4;   // over 1792*3072
  const int n = (int)(e % 3072);
  const size_t S = (size_t)1792*3072;
  float4 a = *(const float4*)(P + e);
  #pragma unroll
  for (int c=1;c<3;c++){
    const float4 p = *(const float4*)(P + c*S + e);
    a.x+=p.x; a.y+=p.y; a.z+=p.z; a.w+=p.w;
  }
  const float4 bb = *(const float4*)(bias + n);
  const float4 gg = *(const float4*)(gate + n);
  const float4 xv = *(const float4*)(x + e);
  float4 o;
  o.x = xv.x + (a.x+bb.x)*gg.x;
  o.y = xv.y + (a.y+bb.y)*gg.y;
  o.z = xv.z + (a.z+bb.z)*gg.z;
  o.w = xv.w + (a.w+bb.w)*gg.w;
  *(float4*)(out + e) = o;
}

// ---------------- host orchestration ----------------
extern "C" void kernel_launch(void* const* d_in, const int* in_sizes, int n_in,
                              void* d_out, int out_size, void* d_ws, size_t ws_size,
                              hipStream_t stream)
{
  (void)in_sizes; (void)n_in; (void)out_size; (void)ws_size;
  const float* x     = (const float*)d_in[0];
  const float* vec   = (const float*)d_in[1];
  const float* ref   = (const float*)d_in[2];
  const float* cosb  = (const float*)d_in[3];
  const float* sinb  = (const float*)d_in[4];
  const float* mod_w = (const float*)d_in[5];
  const float* mod_b = (const float*)d_in[6];
  const float* rf1_w = (const float*)d_in[7];
  const float* rf1_b = (const float*)d_in[8];
  const float* rf2_w = (const float*)d_in[9];
  const float* rf2_b = (const float*)d_in[10];
  const float* rln_g = (const float*)d_in[11];
  const float* rln_b = (const float*)d_in[12];
  const float* lin1_w= (const float*)d_in[13];
  const float* lin1_b= (const float*)d_in[14];
  const float* q_g   = (const float*)d_in[15];
  const float* k_g   = (const float*)d_in[16];
  const float* lin2_w= (const float*)d_in[17];
  const float* lin2_b= (const float*)d_in[18];
  const int*   tmask = (const int*)d_in[19];
  float* out = (float*)d_out;
  char* ws = (char*)d_ws;

  float* modp = (float*)(ws + 0);                    // 9216 f32
  float* part = (float*)(ws + 36864);                // 24*9216 f32
  u16*  w2t   = (u16*)(ws + 921600);                 // 3072 x 15360
  u16*  Qb    = (u16*)(ws + 95293440ll);             // 24 x 1792 x 128
  u16*  Kb    = (u16*)(ws + 106303488ll);            // 24 x 2304 x 128
  u16*  VT    = (u16*)(ws + 120459264ll);            // 24 x 128 x 2304
  u16*  out2  = (u16*)(ws + 134615040ll);            // 1792 x 15360
  u16*  w1t   = (u16*)(ws + 189665280ll);            // 21504 x 3072
  u16*  xc    = (u16*)(ws + 321785856ll);            // 2304 x 3072
  u16*  rf1t  = (u16*)(ws + 335941632ll);            // 3072 x 3072
  u16*  rf2t  = (u16*)(ws + 354816000ll);            // 3072 x 3072
  u16*  refb  = (u16*)(ws + 373690368ll);            // 512 x 3072
  u16*  tb    = (u16*)(ws + 376836096ll);            // 512 x 3072
  float* rp   = (float*)(ws + 386273280ll);          // 6 x 512 x 3072 f32 (pre-lin1 scratch)
  u16*  hbuf  = (u16*)(ws + 335941632ll);            // 2304 x 21504 (qkv cols only)
  float* p2b  = (float*)(ws + 189665280ll);          // 3 x 1792 x 3072 f32 (alias w1t/xc region)

  // 1) modulation GEMV
  modv_part<<<dim3(36,24),256,0,stream>>>(vec, mod_w, part);
  modv_reduce<<<36,256,0,stream>>>(part, mod_b, modp);
  // 2) weight conversions (64x64 tile, float4/u16x4)
  convT<<<dim3(48,48),  256,0,stream>>>(rf1_w, rf1t, 3072, 3072);
  convT<<<dim3(48,48),  256,0,stream>>>(rf2_w, rf2t, 3072, 3072);
  convT<<<dim3(336,48), 256,0,stream>>>(lin1_w, w1t, 3072, 21504);
  convT<<<dim3(48,240), 256,0,stream>>>(lin2_w, w2t, 15360, 3072);
  convertF2B<<<1536,256,0,stream>>>(ref, refb);
  // 3) LN + modulate
  ln_modulate<<<1792,256,0,stream>>>(x, modp, xc);
  // 4) ref MLP (split-K=6) -> fused comb+LN
  gemm_bt<6><<<dim3(24,4,6),256,0,stream>>>(refb, rf1t, nullptr, rp, 512, 3072,3072,3072,
                                            512,512, (long long)512*3072);
  comb_gelu<<<1536,256,0,stream>>>(rp, rf1_b, tb);
  gemm_bt<6><<<dim3(24,4,6),256,0,stream>>>(tb, rf2t, nullptr, rp, 512, 3072,3072,3072,
                                            512,512, (long long)512*3072);
  comb_ln_ref<<<512,256,0,stream>>>(rp, rf2_b, rln_g, rln_b, xc);
  // 5) lin1 sparse map, 8-phase: 636 blocks; qkv cols -> hbuf, mlp cols gelu -> out2
  gemm256<0><<<636,512,0,stream>>>(xc, w1t, lin1_b, hbuf, out2, 3072, 3072, 21504, 84, 636, 0, 636, -1);
  // 6) q/k norm + rope (wave-paired), V transpose (64x64 ushort4)
  qk_prep<<<dim3(2304,24),64,0,stream>>>(hbuf, q_g, k_g, cosb, sinb, Qb, Kb);
  v_transpose<<<dim3(36,2,24),256,0,stream>>>(hbuf, VT);
  // 7) flash attention -> out2[:, :3072]
  flash_attn<<<dim3(14,24),512,0,stream>>>(Qb, Kb, VT, tmask, out2);
  // 8) lin2 split-K=3, 8-phase: M=1792 (7 tiles), N=3072 (12 tiles), Kc=5120 (NT=80), 252 blocks
  gemm256<1><<<252,512,0,stream>>>(out2, w2t, nullptr, p2b, nullptr, 5120, 15360, 3072, 12, 84,
                                   (long long)1792*3072, 252, 0);
  lin2_fin<<<5376,256,0,stream>>>(p2b, x, lin2_b, modp + 6144, out);
}

// Round 18
// 849.277 us; speedup vs baseline: 5.0325x; 1.0045x over previous
//
#include <hip/hip_runtime.h>
#include <cstdint>
#include <cstddef>

typedef unsigned short u16;
typedef unsigned int   u32;
typedef __bf16 bf16_t;
typedef bf16_t bf16x8 __attribute__((ext_vector_type(8)));
typedef float  f32x4  __attribute__((ext_vector_type(4)));
typedef u16    u16x4  __attribute__((ext_vector_type(4)));

// ---- problem constants ----
// H=3072 NH=24 HD=128 MLP_D=12288 IMG=1536 REF=512 TXT=256
// LQ = 1792, L2 = 2304, N1 = 21504, K2 = 15360

__device__ __forceinline__ float b2f(u16 b){ u32 u=((u32)b)<<16; float f; __builtin_memcpy(&f,&u,4); return f; }
__device__ __forceinline__ u16 f2b(float f){ u32 u; __builtin_memcpy(&u,&f,4); u = u + 0x7fffu + ((u>>16)&1u); return (u16)(u>>16); }
// gelu(x) = x * sigmoid(1.5957691*(x+0.044715x^3))
__device__ __forceinline__ float gelu_f(float x){
  const float u2 = 1.5957691216057308f*(x + 0.044715f*x*x*x);
  return x/(1.f + __expf(-u2));
}

__device__ __forceinline__ void gload_lds16(const void* g, void* l){
  __builtin_amdgcn_global_load_lds((const __attribute__((address_space(1))) void*)g,
                                   (__attribute__((address_space(3))) void*)l, 16, 0, 0);
}

template<int NW, bool MX>
__device__ __forceinline__ float bred(float v, float* red){
  #pragma unroll
  for (int o=32;o;o>>=1){ float u=__shfl_down(v,o,64); v = MX? fmaxf(v,u) : v+u; }
  const int t = threadIdx.x;
  if ((t&63)==0) red[t>>6]=v;
  __syncthreads();
  float r = red[0];
  #pragma unroll
  for (int i=1;i<NW;i++) r = MX? fmaxf(r,red[i]) : r+red[i];
  __syncthreads();
  return r;
}

// ---------------- mod GEMV ----------------
__global__ void modv_part(const float* __restrict__ vec, const float* __restrict__ W,
                          float* __restrict__ part){
  __shared__ float s[128];
  const int t = threadIdx.x;
  const int j = blockIdx.x*256 + t;
  const int i0 = blockIdx.y*128;
  if (t < 128){ float v = vec[i0+t]; s[t] = v/(1.f+__expf(-v)); }
  __syncthreads();
  float acc = 0.f;
  #pragma unroll 8
  for (int i=0;i<128;i++) acc += s[i]*W[(size_t)(i0+i)*9216 + j];
  part[(size_t)blockIdx.y*9216 + j] = acc;
}
__global__ void modv_reduce(const float* __restrict__ part, const float* __restrict__ mb,
                            float* __restrict__ modp){
  const int j = blockIdx.x*256 + threadIdx.x;
  float a = mb[j];
  #pragma unroll
  for (int c=0;c<24;c++) a += part[(size_t)c*9216 + j];
  modp[j] = a;
}

// ---------------- fp32 (K x N) -> bf16 transposed (N x K), 64x64 tile ----------------
__global__ __launch_bounds__(256)
void convT(const float* __restrict__ W, u16* __restrict__ Wt, int Kd, int Nd){
  __shared__ float Ls[64][65];
  const int t = threadIdx.x;
  const int n0 = blockIdx.x*64, k0 = blockIdx.y*64;
  const int tr = t>>4;        // 0..15
  const int tc = (t&15)*4;    // 0,4,...,60
  #pragma unroll
  for (int p=0;p<4;p++){
    const int kk = tr + p*16;
    const float4 v = *(const float4*)(W + (size_t)(k0+kk)*Nd + n0 + tc);
    Ls[kk][tc+0]=v.x; Ls[kk][tc+1]=v.y; Ls[kk][tc+2]=v.z; Ls[kk][tc+3]=v.w;
  }
  __syncthreads();
  #pragma unroll
  for (int p=0;p<4;p++){
    const int nn = tr + p*16;
    u16x4 o;
    o.x = f2b(Ls[tc+0][nn]); o.y = f2b(Ls[tc+1][nn]);
    o.z = f2b(Ls[tc+2][nn]); o.w = f2b(Ls[tc+3][nn]);
    *(u16x4*)(Wt + (size_t)(n0+nn)*Kd + k0 + tc) = o;
  }
}

__global__ void convertF2B(const float* __restrict__ src, u16* __restrict__ dst){
  const size_t i = ((size_t)blockIdx.x*256 + threadIdx.x)*4;
  const float4 v = *(const float4*)(src+i);
  u16x4 o; o.x=f2b(v.x); o.y=f2b(v.y); o.z=f2b(v.z); o.w=f2b(v.w);
  *(u16x4*)(dst+i) = o;
}

// ---------------- LN(x)*(1+scale)+shift -> xc (bf16) ----------------
__global__ void ln_modulate(const float* __restrict__ x, const float* __restrict__ modp,
                            u16* __restrict__ xc){
  __shared__ float red[4];
  const int row = blockIdx.x, t = threadIdx.x;
  const float* xr = x + (size_t)row*3072;
  float4 v[3]; float s=0.f, ss=0.f;
  #pragma unroll
  for (int k=0;k<3;k++){
    v[k] = *(const float4*)(xr + t*4 + k*1024);
    s  += v[k].x+v[k].y+v[k].z+v[k].w;
    ss += v[k].x*v[k].x+v[k].y*v[k].y+v[k].z*v[k].z+v[k].w*v[k].w;
  }
  s  = bred<4,false>(s, red);
  ss = bred<4,false>(ss, red);
  const float mean = s*(1.f/3072.f);
  const float inv = rsqrtf(ss*(1.f/3072.f)-mean*mean + 1e-6f);
  const int orow = row<1536 ? row : row+512;
  u16* o = xc + (size_t)orow*3072;
  const float* shiftp = modp; const float* scalep = modp+3072;
  #pragma unroll
  for (int k=0;k<3;k++){
    const int j = t*4 + k*1024;
    const float4 sc = *(const float4*)(scalep+j);
    const float4 sh = *(const float4*)(shiftp+j);
    u16x4 ov;
    ov.x = f2b((v[k].x-mean)*inv*(1.f+sc.x)+sh.x);
    ov.y = f2b((v[k].y-mean)*inv*(1.f+sc.y)+sh.y);
    ov.z = f2b((v[k].z-mean)*inv*(1.f+sc.z)+sh.z);
    ov.w = f2b((v[k].w-mean)*inv*(1.f+sc.w)+sh.w);
    *(u16x4*)(o+j) = ov;
  }
}

// ---------------- fused: sum 6 split-K partials + rf2_b, then LN(.)*g+b -> xc rows [1536,2048) ----------------
__global__ void comb_ln_ref(const float* __restrict__ P, const float* __restrict__ rb,
                            const float* __restrict__ g, const float* __restrict__ be,
                            u16* __restrict__ xc){
  __shared__ float red[4];
  const int row = blockIdx.x, t = threadIdx.x;
  const size_t S = (size_t)512*3072;
  float4 v[3]; float s=0.f, ss=0.f;
  #pragma unroll
  for (int k=0;k<3;k++){
    const int j = t*4 + k*1024;
    const size_t e = (size_t)row*3072 + j;
    float4 a = *(const float4*)(P + e);
    #pragma unroll
    for (int c=1;c<6;c++){
      const float4 p = *(const float4*)(P + c*S + e);
      a.x+=p.x; a.y+=p.y; a.z+=p.z; a.w+=p.w;
    }
    const float4 bb = *(const float4*)(rb + j);
    a.x+=bb.x; a.y+=bb.y; a.z+=bb.z; a.w+=bb.w;
    v[k] = a;
    s  += a.x+a.y+a.z+a.w;
    ss += a.x*a.x+a.y*a.y+a.z*a.z+a.w*a.w;
  }
  s  = bred<4,false>(s, red);
  ss = bred<4,false>(ss, red);
  const float mean = s*(1.f/3072.f);
  const float inv = rsqrtf(ss*(1.f/3072.f)-mean*mean + 1e-6f);
  u16* o = xc + (size_t)(1536+row)*3072;
  #pragma unroll
  for (int k=0;k<3;k++){
    const int j = t*4 + k*1024;
    const float4 gv = *(const float4*)(g+j);
    const float4 bv = *(const float4*)(be+j);
    u16x4 ov;
    ov.x = f2b((v[k].x-mean)*inv*gv.x+bv.x);
    ov.y = f2b((v[k].y-mean)*inv*gv.y+bv.y);
    ov.z = f2b((v[k].z-mean)*inv*gv.z+bv.z);
    ov.w = f2b((v[k].w-mean)*inv*gv.w+bv.w);
    *(u16x4*)(o+j) = ov;
  }
}

// ---------------- RMS-norm + RoPE on q,k from h (64 threads, wave-shuffle, paired) ----------------
__global__ void qk_prep(const u16* __restrict__ h, const float* __restrict__ qg,
                        const float* __restrict__ kg, const float* __restrict__ cosb,
                        const float* __restrict__ sinb, u16* __restrict__ Q,
                        u16* __restrict__ Kb){
  const int row = blockIdx.x, hd = blockIdx.y, p = threadIdx.x; // 64 threads, pair p
  const u16* hr = h + (size_t)row*21504;
  const int d0 = p*2;
  const u32 kp = *(const u32*)(hr + 3072 + hd*128 + d0);
  const bool doq = (row < 1536) || (row >= 2048);
  const u32 qp = doq ? *(const u32*)(hr + hd*128 + d0) : 0u;
  const float k0 = b2f((u16)(kp&0xffffu)), k1 = b2f((u16)(kp>>16));
  const float q0 = b2f((u16)(qp&0xffffu)), q1 = b2f((u16)(qp>>16));
  float a = k0*k0 + k1*k1;
  float b = q0*q0 + q1*q1;
  #pragma unroll
  for (int o=32;o;o>>=1){ a += __shfl_xor(a,o,64); b += __shfl_xor(b,o,64); }
  const float kinv = rsqrtf(a*(1.f/128.f) + 1e-6f);
  const float qinv = rsqrtf(b*(1.f/128.f) + 1e-6f);
  float kn0 = k0*kinv*kg[d0], kn1 = k1*kinv*kg[d0+1];
  float qn0 = q0*qinv*qg[d0], qn1 = q1*qinv*qg[d0+1];
  if (row < 1536){
    const float c0 = cosb[row*128+d0], c1 = cosb[row*128+d0+1];
    const float s0 = sinb[row*128+d0], s1 = sinb[row*128+d0+1];
    const float tk0 = kn0*c0 - kn1*s0;
    const float tk1 = kn1*c1 + kn0*s1;
    kn0 = tk0; kn1 = tk1;
    const float tq0 = qn0*c0 - qn1*s0;
    const float tq1 = qn1*c1 + qn0*s1;
    qn0 = tq0; qn1 = tq1;
  }
  *(u32*)(Kb + ((size_t)hd*2304 + row)*128 + d0) = (u32)f2b(kn0) | ((u32)f2b(kn1)<<16);
  if (doq){
    const int qrow = row<1536 ? row : row-512;
    *(u32*)(Q + ((size_t)hd*1792 + qrow)*128 + d0) = (u32)f2b(qn0) | ((u32)f2b(qn1)<<16);
  }
}

// ---------------- V transpose: 64x64 tile, ushort4 ----------------
__global__ __launch_bounds__(256)
void v_transpose(const u16* __restrict__ h, u16* __restrict__ VT){
  __shared__ u16 Ls[64][68];
  const int t = threadIdx.x;
  const int l0 = blockIdx.x*64, d0 = blockIdx.y*64, hd = blockIdx.z;
  const int tr = t>>4, tc = (t&15)*4;
  #pragma unroll
  for (int p=0;p<4;p++){
    const int kk = tr + p*16;
    const ushort4 v = *(const ushort4*)(h + (size_t)(l0+kk)*21504 + 6144 + hd*128 + d0 + tc);
    Ls[kk][tc] = v.x; Ls[kk][tc+1] = v.y; Ls[kk][tc+2] = v.z; Ls[kk][tc+3] = v.w;
  }
  __syncthreads();
  #pragma unroll
  for (int p=0;p<4;p++){
    const int nn = tr + p*16;
    ushort4 o;
    o.x = Ls[tc][nn]; o.y = Ls[tc+1][nn]; o.z = Ls[tc+2][nn]; o.w = Ls[tc+3][nn];
    *(ushort4*)(VT + ((size_t)hd*128 + d0+nn)*2304 + l0 + tc) = o;
  }
}

// ---------------- 128x128 2-barrier GEMM (small shapes; EPI 6 = f32 split-K partial) ----------------
template<int EPI>
__global__ __launch_bounds__(256)
void gemm_bt(const u16* __restrict__ A, const u16* __restrict__ Bt,
             const float* __restrict__ bias, void* __restrict__ Cv,
             int K, int ldA, int ldB, int ldC,
             long long sA, long long sB, long long sC)
{
  __shared__ u16 As[128*32];
  __shared__ u16 Bs[128*32];
  const int t = threadIdx.x;
  const int w = t>>6, lane = t&63;
  const int bm = blockIdx.y, bn = blockIdx.x, bz = blockIdx.z;
  const u16* Ab = A + (size_t)((long long)bz*sA) + (size_t)bm*128*ldA;
  const u16* Bb = Bt + (size_t)((long long)bz*sB) + (size_t)bn*128*ldB;
  const int wm = w>>1, wn = w&1;
  const int lr = lane&15, lk = lane>>4;
  const int row0 = t>>2, kp0 = (t&3)*8;
  char* AsB = (char*)As; char* BsB = (char*)Bs;
  const int off0 = w*1024;
  const int off1 = 4096 + w*1024;
  f32x4 acc[4][4] = {};

  for (int kt = 0; kt < K; kt += 32){
    __syncthreads();
    gload_lds16(Ab + (size_t)row0*ldA + kt + kp0,      AsB + off0);
    gload_lds16(Ab + (size_t)(row0+64)*ldA + kt + kp0, AsB + off1);
    gload_lds16(Bb + (size_t)row0*ldB + kt + kp0,      BsB + off0);
    gload_lds16(Bb + (size_t)(row0+64)*ldB + kt + kp0, BsB + off1);
    __syncthreads();
    bf16x8 av[4], bv[4];
    #pragma unroll
    for (int i=0;i<4;i++) av[i] = *(const bf16x8*)(As + (wm*64+i*16+lr)*32 + lk*8);
    #pragma unroll
    for (int j=0;j<4;j++) bv[j] = *(const bf16x8*)(Bs + (wn*64+j*16+lr)*32 + lk*8);
    #pragma unroll
    for (int i=0;i<4;i++)
      #pragma unroll
      for (int j=0;j<4;j++)
        acc[i][j] = __builtin_amdgcn_mfma_f32_16x16x32_bf16(av[i], bv[j], acc[i][j], 0,0,0);
  }

  const int mBase = bm*128 + wm*64;
  const int nBase = bn*128 + wn*64;
  #pragma unroll
  for (int i=0;i<4;i++){
    #pragma unroll
    for (int j=0;j<4;j++){
      #pragma unroll
      for (int r=0;r<4;r++){
        const int m = mBase + i*16 + lk*4 + r;
        const int n = nBase + j*16 + lr;
        const float v = acc[i][j][r];
        const long long idx = (long long)bz*sC + (long long)m*ldC + n;
        if (EPI==6){
          ((float*)Cv)[idx] = v;
        } else {
          ((u16*)Cv)[idx] = f2b(v + bias[n]);
        }
      }
    }
  }
}

// ---------------- split-K combine for ref MLP layer 1 (gelu) ----------------
__global__ void comb_gelu(const float* __restrict__ P, const float* __restrict__ b,
                          u16* __restrict__ o){
  const size_t e = ((size_t)blockIdx.x*256 + threadIdx.x)*4;   // over 512*3072
  const int n = (int)(e % 3072);
  const size_t S = (size_t)512*3072;
  float4 a = *(const float4*)(P + e);
  #pragma unroll
  for (int c=1;c<6;c++){
    const float4 p = *(const float4*)(P + c*S + e);
    a.x+=p.x; a.y+=p.y; a.z+=p.z; a.w+=p.w;
  }
  const float4 bb = *(const float4*)(b + n);
  u16x4 ov;
  ov.x = f2b(gelu_f(a.x+bb.x)); ov.y = f2b(gelu_f(a.y+bb.y));
  ov.z = f2b(gelu_f(a.z+bb.z)); ov.w = f2b(gelu_f(a.w+bb.w));
  *(u16x4*)(o + e) = ov;
}

// ================= 256x256 GEMM, m201 8-phase schedule (T1+T2+T3+T4+T5) =================
// 2 K-tiles per iteration, 8 phases; counted vmcnt(4) only at phases 4 and 8.
// Staging ledger (tile tau -> slot tau&1):
//  P1: A(t+1)->s1A   P2: B0(t+2)->s0B  P3: B1(t+2)->s0B
//  P5: A0(t+2)->s0A  P6: A1(t+2)->s0A  P7: B0(t+3)->s1B  P8: B1(t+3)->s1B
// Region free-times: s0B after P1, s0A after P4, s1B after P5, s1A after P8. NT must be EVEN.
// CEPI 0: C(bf16)=acc+bias; lin1 mlp tiles (gm==-1 && bn>=36) -> Cv2=out2 with gelu.
// CEPI 1: C(f32 at sk*sC)=acc (split-K partial).
// gm>0: grouped bands; gm==0: split-K; gm==-1: lin1 sparse 636-tile map. All XCD-swizzled.
#define G256_BAR()  __builtin_amdgcn_s_barrier()
#define G256_LGKM() do{ asm volatile("s_waitcnt lgkmcnt(0)" ::: "memory"); \
                        __builtin_amdgcn_sched_barrier(0); }while(0)
#define G256_VM4()  asm volatile("s_waitcnt vmcnt(4)" ::: "memory")
#define G256_VM0()  asm volatile("s_waitcnt vmcnt(0)" ::: "memory")

__device__ __forceinline__ void lin1_map(int tw, int& bm, int& bn){
  if (tw < 504){
    const int band = tw/252; const int rr = tw - band*252;
    bn = rr/3; bm = band*3 + (rr - bn*3);
  } else if (tw < 588){
    bm = 8; bn = tw - 504;
  } else {
    const int rem = tw - 588;
    bm = 6 + (rem&1); bn = 12 + (rem>>1);
  }
}

template<int CEPI>
__global__ __launch_bounds__(512,2)
void gemm256(const u16* __restrict__ A, const u16* __restrict__ Bt,
             const float* __restrict__ bias, void* __restrict__ Cv, void* __restrict__ Cv2,
             int Kc, int ld, int ldC, int nbn, int ntile, long long sC, int nwg, int gm)
{
  __shared__ char smem[131072];
  const int t = threadIdx.x;
  const int wid = t>>6, lane = t&63;
  const int lr = lane&15, lk = lane>>4;
  const int wm = wid>>2, wn = wid&3;

  // bijective XCD swizzle (m204)
  const int orig = blockIdx.x;
  const int q8 = nwg>>3, r8 = nwg&7;
  const int xcd = orig&7, jj = orig>>3;
  const int wg = (xcd<r8 ? xcd*(q8+1) : r8*(q8+1) + (xcd-r8)*q8) + jj;
  int sk, bm, bn;
  if (gm == -1){
    sk = 0; lin1_map(wg, bm, bn);
  } else if (gm > 0){
    const int band = wg / (gm*nbn);
    const int rr = wg - band*(gm*nbn);
    bn = rr / gm;
    bm = band*gm + (rr - bn*gm);
    sk = 0;
  } else {
    sk = wg / ntile;
    const int rem = wg - sk*ntile;
    bm = rem / nbn; bn = rem % nbn;
  }

  const u16* Agl = A  + (size_t)bm*256*ld + (size_t)sk*Kc;
  const u16* Bgl = Bt + (size_t)bn*256*ld + (size_t)sk*Kc;
  const int NT = Kc>>6;     // even
  const int NI = NT>>1;

  // staging: dest idx d0 in [0,512): row sr=d0>>3, dest 16B-slot=d0&7;
  // global source slot = dest_slot ^ (sr&7) (inverse swizzle, rule 21).
  const int d0 = wid*64 + lane;
  const int sr = d0>>3;
  const size_t soff = (size_t)sr*ld + (size_t)(((d0&7)^(sr&7))<<3);
  // read-side swizzled 16B-slot byte offsets
  const int xsl0 = ((lk    ) ^ (lr&7))<<4;   // ks=0
  const int xsl1 = ((lk | 4) ^ (lr&7))<<4;   // ks=1

  char* s0A = smem;
  char* s0B = smem + 32768;
  char* s1A = smem + 65536;
  char* s1B = smem + 98304;

  f32x4 acc[8][4] = {};
  bf16x8 bv[4][2];

  auto STAGE = [&](const u16* g, int h, int kt, char* ldsMat){
    const u16* s0 = g + (size_t)(h*128)*ld + kt + soff;
    char* l0 = ldsMat + h*16384 + wid*1024;
    gload_lds16(s0, l0);
    gload_lds16(s0 + (size_t)64*ld, l0 + 8192);
  };

  // ---- prologue: A(0)->s0A, B(0)->s0B, B(1)->s1B; leave B(1) in flight ----
  STAGE(Agl, 0, 0, s0A);
  STAGE(Agl, 1, 0, s0A);
  STAGE(Bgl, 0, 0, s0B);
  STAGE(Bgl, 1, 0, s0B);
  STAGE(Bgl, 0, 64, s1B);
  STAGE(Bgl, 1, 64, s1B);
  G256_VM4();
  G256_BAR();

#define G256_PH(SA, Q, READB, SB, STG, TAILV)                                   \
  do{                                                                           \
    const char* ab = SA + (wm*128 + (Q)*32 + lr)*128;                           \
    bf16x8 a0 = *(const bf16x8*)(ab + xsl0);                                    \
    bf16x8 a1 = *(const bf16x8*)(ab + xsl1);                                    \
    bf16x8 a2 = *(const bf16x8*)(ab + 2048 + xsl0);                             \
    bf16x8 a3 = *(const bf16x8*)(ab + 2048 + xsl1);                             \
    if (READB){                                                                 \
      _Pragma("unroll")                                                         \
      for (int j=0;j<4;j++){                                                    \
        const char* bb = SB + (wn*64 + j*16 + lr)*128;                          \
        bv[j][0] = *(const bf16x8*)(bb + xsl0);                                 \
        bv[j][1] = *(const bf16x8*)(bb + xsl1);                                 \
      }                                                                         \
    }                                                                           \
    STG;                                                                        \
    G256_BAR();                                                                 \
    G256_LGKM();                                                                \
    __builtin_amdgcn_s_setprio(1);                                              \
    _Pragma("unroll")                                                           \
    for (int j=0;j<4;j++){                                                      \
      acc[(Q)*2+0][j] = __builtin_amdgcn_mfma_f32_16x16x32_bf16(a0, bv[j][0], acc[(Q)*2+0][j], 0,0,0); \
      acc[(Q)*2+0][j] = __builtin_amdgcn_mfma_f32_16x16x32_bf16(a1, bv[j][1], acc[(Q)*2+0][j], 0,0,0); \
      acc[(Q)*2+1][j] = __builtin_amdgcn_mfma_f32_16x16x32_bf16(a2, bv[j][0], acc[(Q)*2+1][j], 0,0,0); \
      acc[(Q)*2+1][j] = __builtin_amdgcn_mfma_f32_16x16x32_bf16(a3, bv[j][1], acc[(Q)*2+1][j], 0,0,0); \
    }                                                                           \
    __builtin_amdgcn_s_setprio(0);                                              \
    TAILV;                                                                      \
    G256_BAR();                                                                 \
  }while(0)

  for (int it2 = 0; it2 < NI; ++it2){
    const int t0 = it2*2;
    const bool s2 = (t0+2) < NT, s3 = (t0+3) < NT;
    const int k1 = (t0+1)<<6, k2 = (t0+2)<<6, k3 = (t0+3)<<6;

    // tile t0 (slot0)
    G256_PH(s0A, 0, 1, s0B, { STAGE(Agl,0,k1,s1A); STAGE(Agl,1,k1,s1A); }, );
    G256_PH(s0A, 1, 0, s0B, if (s2) STAGE(Bgl,0,k2,s0B), );
    G256_PH(s0A, 2, 0, s0B, if (s2) STAGE(Bgl,1,k2,s0B), );
    G256_PH(s0A, 3, 0, s0B, , if (s2) G256_VM4(); else G256_VM0(); );
    // tile t0+1 (slot1)
    G256_PH(s1A, 0, 1, s1B, if (s2) STAGE(Agl,0,k2,s0A), );
    G256_PH(s1A, 1, 0, s1B, if (s2) STAGE(Agl,1,k2,s0A), );
    G256_PH(s1A, 2, 0, s1B, if (s3) STAGE(Bgl,0,k3,s1B), );
    G256_PH(s1A, 3, 0, s1B, if (s3) STAGE(Bgl,1,k3,s1B),
            if (s3) G256_VM4(); else G256_VM0(); );
  }
#undef G256_PH

  // ---- epilogue ----
  const int mB = bm*256 + wm*128 + lk*4;
  const int nB = bn*256 + wn*64 + lr;
  if (CEPI==0 && gm==-1 && bn >= 36){
    // lin1 mlp tiles: block-uniform; bm in {0..5,8}; write gelu -> out2 (ld 15360)
    const int mq = (bm <= 5) ? mB : (mB - 512);
    #pragma unroll
    for (int fi=0; fi<8; fi++){
      #pragma unroll
      for (int j=0; j<4; j++){
        const int n = nB + j*16;
        const float bb = bias[n];
        #pragma unroll
        for (int r=0;r<4;r++){
          ((u16*)Cv2)[(size_t)(mq + fi*16 + r)*15360 + (n - 6144)] = f2b(gelu_f(acc[fi][j][r] + bb));
        }
      }
    }
  } else {
    #pragma unroll
    for (int fi=0; fi<8; fi++){
      #pragma unroll
      for (int j=0; j<4; j++){
        const int n = nB + j*16;
        const float bb = (CEPI==0) ? bias[n] : 0.f;
        #pragma unroll
        for (int r=0;r<4;r++){
          const int m = mB + fi*16 + r;
          if (CEPI==0){
            ((u16*)Cv)[(size_t)m*ldC + n] = f2b(acc[fi][j][r] + bb);
          } else {
            ((float*)Cv)[(size_t)sk*sC + (size_t)m*ldC + n] = acc[fi][j][r];
          }
        }
      }
    }
  }
}

// ================= flash attention (80 KB LDS, 2 blocks/CU, XCD-local heads) =================
// 1-D grid 336: b -> xcd=b&7, j=b>>3, head=3*xcd+j/14, qt=j%14 (bijective).
// Same-head blocks land on one XCD (dispatch round-robin) -> K/V L2-resident
// (3 heads x 2.36 MB = 3.5 MB <= 4 MB per-XCD L2).
__global__ __launch_bounds__(512,4)
void flash_attn(const u16* __restrict__ Qb, const u16* __restrict__ Kb,
                const u16* __restrict__ VT, const int* __restrict__ tmask,
                u16* __restrict__ out2)
{
  __shared__ __attribute__((aligned(16))) char smf[81920];
  char* Ks0 = smf;            // 2 x [64][128] = 32 KB
  char* Vs0 = smf + 32768;    // 2 x [128 d][64 k] = 32 KB (Q temp at start)
  char* Ps  = smf + 65536;    // [128 q][64 k] = 16 KB
  const int t = threadIdx.x, wid = t>>6, lane = t&63;
  const int lr = lane&15, hi = lane>>4;
  const int b = blockIdx.x;
  const int xcd8 = b & 7, jj = b >> 3;
  const int head = 3*xcd8 + jj/14;
  const int qt = jj % 14;
  const int q0 = qt*128;
  const u16* Qg = Qb + ((size_t)head*1792 + q0)*128;
  const u16* Kg = Kb + (size_t)head*2304*128;
  const u16* Vg = VT + (size_t)head*128*2304;
  const float SCALE = 0.08838834764831845f;

  u32 kbits = 0;
  #pragma unroll
  for (int i=0;i<16;i++) kbits |= (u32)(tmask[i*16 + lr] != 0) << i;
  int fqr[4];
  #pragma unroll
  for (int r=0;r<4;r++){
    const int q = q0 + wid*16 + hi*4 + r;
    fqr[r] = (q < 1536) ? 1 : (tmask[q-1536] != 0);
  }

  // ---- stage Q (temp in Vs0) + K tile 0 ----
  #pragma unroll
  for (int c=0;c<4;c++){
    const int s = c*512 + wid*64 + lane;
    const int row = s>>4, dsl = s&15;
    gload_lds16(Qg + (size_t)row*128 + ((dsl ^ (row&7))<<3),
                Vs0 + (size_t)(c*512 + wid*64)*16);
  }
  #pragma unroll
  for (int c=0;c<2;c++){
    const int s = c*512 + wid*64 + lane;
    const int row = s>>4, dsl = s&15;
    gload_lds16(Kg + (size_t)row*128 + ((dsl ^ (row&7))<<3),
                Ks0 + (size_t)(c*512 + wid*64)*16);
  }
  asm volatile("s_waitcnt vmcnt(0)" ::: "memory");
  __syncthreads();

  // hoist Q A-frags from Vs0 (temp)
  bf16x8 av[4];
  {
    const int row = wid*16 + lr;
    #pragma unroll
    for (int ks=0;ks<4;ks++)
      av[ks] = *(const bf16x8*)(Vs0 + row*256 + (((ks*4+hi) ^ (row&7))<<4));
  }
  asm volatile("s_waitcnt lgkmcnt(0)" ::: "memory");
  __builtin_amdgcn_sched_barrier(0);
  __syncthreads();

  // ---- stage V tile 0 (overwrites Q temp) ----
  #pragma unroll
  for (int c=0;c<2;c++){
    const int s = c*512 + wid*64 + lane;
    const int row = s>>3, dsl = s&7;
    gload_lds16(Vg + (size_t)row*2304 + ((dsl ^ (row&7))<<3),
                Vs0 + (size_t)(c*512 + wid*64)*16);
  }
  asm volatile("s_waitcnt vmcnt(0)" ::: "memory");
  __syncthreads();

  f32x4 acc[8] = {};
  float m_[4], l_[4];
  #pragma unroll
  for (int r=0;r<4;r++){ m_[r] = -3e38f; l_[r] = 0.f; }

  for (int kt = 0; kt < 36; ++kt){
    char* Kc = Ks0 + (kt&1)*16384;
    char* Vc = Vs0 + (kt&1)*16384;
    if (kt+1 < 36){
      char* Kn = Ks0 + ((kt+1)&1)*16384;
      char* Vn = Vs0 + ((kt+1)&1)*16384;
      #pragma unroll
      for (int c=0;c<2;c++){
        const int s = c*512 + wid*64 + lane;
        { const int row = s>>4, dsl = s&15;
          gload_lds16(Kg + (size_t)((kt+1)*64 + row)*128 + ((dsl ^ (row&7))<<3),
                      Kn + (size_t)(c*512 + wid*64)*16); }
        { const int row = s>>3, dsl = s&7;
          gload_lds16(Vg + (size_t)row*2304 + (kt+1)*64 + ((dsl ^ (row&7))<<3),
                      Vn + (size_t)(c*512 + wid*64)*16); }
      }
    }
    f32x4 sacc[4] = {};
    #pragma unroll
    for (int ks=0;ks<4;ks++){
      #pragma unroll
      for (int j=0;j<4;j++){
        const int row = j*16 + lr;
        bf16x8 bk = *(const bf16x8*)(Kc + row*256 + (((ks*4+hi) ^ (row&7))<<4));
        sacc[j] = __builtin_amdgcn_mfma_f32_16x16x32_bf16(av[ks], bk, sacc[j], 0,0,0);
      }
    }
    int gkj[4];
    #pragma unroll
    for (int j=0;j<4;j++)
      gkj[j] = (kt < 32) ? 1 : (int)((kbits >> ((kt-32)*4 + j)) & 1u);
    float p[4][4]; bool alw[4][4];
    float mt[4] = {-3e38f,-3e38f,-3e38f,-3e38f};
    #pragma unroll
    for (int j=0;j<4;j++){
      #pragma unroll
      for (int r=0;r<4;r++){
        const float s = sacc[j][r]*SCALE;
        const bool a = (fqr[r] == gkj[j]);
        alw[j][r] = a; p[j][r] = s;
        if (a) mt[r] = fmaxf(mt[r], s);
      }
    }
    #pragma unroll
    for (int r=0;r<4;r++){
      #pragma unroll
      for (int o=1;o<16;o<<=1) mt[r] = fmaxf(mt[r], __shfl_xor(mt[r], o, 64));
      const float nm = fmaxf(m_[r], mt[r]);
      const float cr = __expf(m_[r] - nm);
      m_[r] = nm;
      l_[r] *= cr;
      #pragma unroll
      for (int jp=0;jp<8;jp++) acc[jp][r] *= cr;
    }
    float rs[4] = {0.f,0.f,0.f,0.f};
    #pragma unroll
    for (int j=0;j<4;j++){
      #pragma unroll
      for (int r=0;r<4;r++){
        const float pv = alw[j][r] ? __expf(p[j][r] - m_[r]) : 0.f;
        p[j][r] = pv; rs[r] += pv;
      }
    }
    #pragma unroll
    for (int r=0;r<4;r++){
      #pragma unroll
      for (int o=1;o<16;o<<=1) rs[r] += __shfl_xor(rs[r], o, 64);
      l_[r] += rs[r];
    }
    #pragma unroll
    for (int j=0;j<4;j++){
      #pragma unroll
      for (int r=0;r<4;r++){
        const int q = wid*16 + hi*4 + r;
        const int k = j*16 + lr;
        *(u16*)(Ps + q*128 + (((k>>3) ^ (q&7))<<4) + (k&7)*2) = f2b(p[j][r]);
      }
    }
    asm volatile("s_waitcnt lgkmcnt(0)" ::: "memory");
    __builtin_amdgcn_sched_barrier(0);
    bf16x8 pa[2];
    {
      const int row = wid*16 + lr;
      #pragma unroll
      for (int ks2=0;ks2<2;ks2++)
        pa[ks2] = *(const bf16x8*)(Ps + row*128 + (((ks2*4+hi) ^ (row&7))<<4));
    }
    #pragma unroll
    for (int ks2=0;ks2<2;ks2++){
      #pragma unroll
      for (int jp=0;jp<8;jp++){
        const int row = jp*16 + lr;
        bf16x8 bvv = *(const bf16x8*)(Vc + row*128 + (((ks2*4+hi) ^ (row&7))<<4));
        acc[jp] = __builtin_amdgcn_mfma_f32_16x16x32_bf16(pa[ks2], bvv, acc[jp], 0,0,0);
      }
    }
    asm volatile("s_waitcnt vmcnt(0)" ::: "memory");
    __syncthreads();
  }

  float inv[4];
  #pragma unroll
  for (int r=0;r<4;r++) inv[r] = 1.f/l_[r];
  #pragma unroll
  for (int jp=0;jp<8;jp++){
    #pragma unroll
    for (int r=0;r<4;r++){
      const size_t q = q0 + wid*16 + hi*4 + r;
      out2[q*15360 + head*128 + jp*16 + lr] = f2b(acc[jp][r]*inv[r]);
    }
  }
}

// ---------------- lin2 finish: out = x + (p0+p1+p2+bias)*gate ----------------
__global__ void lin2_fin(const float* __restrict__ P, const float* __restrict__ x,
                         const float* __restrict__ bias, const float* __restrict__ gate,
                         float* __restrict__ out){
  const size_t e = ((size_t)blockIdx.x*256 + threadIdx.x)*4;   // over 1792*3072
  const int n = (int)(e % 3072);
  const size_t S = (size_t)1792*3072;
  float4 a = *(const float4*)(P + e);
  #pragma unroll
  for (int c=1;c<3;c++){
    const float4 p = *(const float4*)(P + c*S + e);
    a.x+=p.x; a.y+=p.y; a.z+=p.z; a.w+=p.w;
  }
  const float4 bb = *(const float4*)(bias + n);
  const float4 gg = *(const float4*)(gate + n);
  const float4 xv = *(const float4*)(x + e);
  float4 o;
  o.x = xv.x + (a.x+bb.x)*gg.x;
  o.y = xv.y + (a.y+bb.y)*gg.y;
  o.z = xv.z + (a.z+bb.z)*gg.z;
  o.w = xv.w + (a.w+bb.w)*gg.w;
  *(float4*)(out + e) = o;
}

// ---------------- host orchestration ----------------
extern "C" void kernel_launch(void* const* d_in, const int* in_sizes, int n_in,
                              void* d_out, int out_size, void* d_ws, size_t ws_size,
                              hipStream_t stream)
{
  (void)in_sizes; (void)n_in; (void)out_size; (void)ws_size;
  const float* x     = (const float*)d_in[0];
  const float* vec   = (const float*)d_in[1];
  const float* ref   = (const float*)d_in[2];
  const float* cosb  = (const float*)d_in[3];
  const float* sinb  = (const float*)d_in[4];
  const float* mod_w = (const float*)d_in[5];
  const float* mod_b = (const float*)d_in[6];
  const float* rf1_w = (const float*)d_in[7];
  const float* rf1_b = (const float*)d_in[8];
  const float* rf2_w = (const float*)d_in[9];
  const float* rf2_b = (const float*)d_in[10];
  const float* rln_g = (const float*)d_in[11];
  const float* rln_b = (const float*)d_in[12];
  const float* lin1_w= (const float*)d_in[13];
  const float* lin1_b= (const float*)d_in[14];
  const float* q_g   = (const float*)d_in[15];
  const float* k_g   = (const float*)d_in[16];
  const float* lin2_w= (const float*)d_in[17];
  const float* lin2_b= (const float*)d_in[18];
  const int*   tmask = (const int*)d_in[19];
  float* out = (float*)d_out;
  char* ws = (char*)d_ws;

  float* modp = (float*)(ws + 0);                    // 9216 f32
  float* part = (float*)(ws + 36864);                // 24*9216 f32
  u16*  w2t   = (u16*)(ws + 921600);                 // 3072 x 15360
  u16*  Qb    = (u16*)(ws + 95293440ll);             // 24 x 1792 x 128
  u16*  Kb    = (u16*)(ws + 106303488ll);            // 24 x 2304 x 128
  u16*  VT    = (u16*)(ws + 120459264ll);            // 24 x 128 x 2304
  u16*  out2  = (u16*)(ws + 134615040ll);            // 1792 x 15360
  u16*  w1t   = (u16*)(ws + 189665280ll);            // 21504 x 3072
  u16*  xc    = (u16*)(ws + 321785856ll);            // 2304 x 3072
  u16*  rf1t  = (u16*)(ws + 335941632ll);            // 3072 x 3072
  u16*  rf2t  = (u16*)(ws + 354816000ll);            // 3072 x 3072
  u16*  refb  = (u16*)(ws + 373690368ll);            // 512 x 3072
  u16*  tb    = (u16*)(ws + 376836096ll);            // 512 x 3072
  float* rp   = (float*)(ws + 386273280ll);          // 6 x 512 x 3072 f32 (pre-lin1 scratch)
  u16*  hbuf  = (u16*)(ws + 335941632ll);            // 2304 x 21504 (qkv cols only)
  float* p2b  = (float*)(ws + 189665280ll);          // 3 x 1792 x 3072 f32 (alias w1t/xc region)

  // 1) modulation GEMV
  modv_part<<<dim3(36,24),256,0,stream>>>(vec, mod_w, part);
  modv_reduce<<<36,256,0,stream>>>(part, mod_b, modp);
  // 2) weight conversions (64x64 tile, float4/u16x4)
  convT<<<dim3(48,48),  256,0,stream>>>(rf1_w, rf1t, 3072, 3072);
  convT<<<dim3(48,48),  256,0,stream>>>(rf2_w, rf2t, 3072, 3072);
  convT<<<dim3(336,48), 256,0,stream>>>(lin1_w, w1t, 3072, 21504);
  convT<<<dim3(48,240), 256,0,stream>>>(lin2_w, w2t, 15360, 3072);
  convertF2B<<<1536,256,0,stream>>>(ref, refb);
  // 3) LN + modulate
  ln_modulate<<<1792,256,0,stream>>>(x, modp, xc);
  // 4) ref MLP (split-K=6) -> fused comb+LN
  gemm_bt<6><<<dim3(24,4,6),256,0,stream>>>(refb, rf1t, nullptr, rp, 512, 3072,3072,3072,
                                            512,512, (long long)512*3072);
  comb_gelu<<<1536,256,0,stream>>>(rp, rf1_b, tb);
  gemm_bt<6><<<dim3(24,4,6),256,0,stream>>>(tb, rf2t, nullptr, rp, 512, 3072,3072,3072,
                                            512,512, (long long)512*3072);
  comb_ln_ref<<<512,256,0,stream>>>(rp, rf2_b, rln_g, rln_b, xc);
  // 5) lin1 sparse map, 8-phase: 636 blocks; qkv cols -> hbuf, mlp cols gelu -> out2
  gemm256<0><<<636,512,0,stream>>>(xc, w1t, lin1_b, hbuf, out2, 3072, 3072, 21504, 84, 636, 0, 636, -1);
  // 6) q/k norm + rope (wave-paired), V transpose (64x64 ushort4)
  qk_prep<<<dim3(2304,24),64,0,stream>>>(hbuf, q_g, k_g, cosb, sinb, Qb, Kb);
  v_transpose<<<dim3(36,2,24),256,0,stream>>>(hbuf, VT);
  // 7) flash attention -> out2[:, :3072]  (XCD-local heads: 1-D grid 336)
  flash_attn<<<336,512,0,stream>>>(Qb, Kb, VT, tmask, out2);
  // 8) lin2 split-K=3, 8-phase: M=1792 (7 tiles), N=3072 (12 tiles), Kc=5120 (NT=80), 252 blocks
  gemm256<1><<<252,512,0,stream>>>(out2, w2t, nullptr, p2b, nullptr, 5120, 15360, 3072, 12, 84,
                                   (long long)1792*3072, 252, 0);
  lin2_fin<<<5376,256,0,stream>>>(p2b, x, lin2_b, modp + 6144, out);
}